// Round 2
// baseline (903.086 us; speedup 1.0000x reference)
//
#include <hip/hip_runtime.h>

typedef unsigned short u16;
typedef __attribute__((ext_vector_type(8))) short short8;
typedef __attribute__((ext_vector_type(8))) unsigned short ushort8;
typedef __attribute__((ext_vector_type(4))) float f32x4;

#define D_MODEL 768
#define D_INNER 1536
#define D_XZ    3072
#define D_STATE 16
#define DT_RANK 48
#define NROW    2048   // B*T
#define SEQ     1024

__device__ __forceinline__ float bf2f(u16 u) {
    union { unsigned int i; float f; } v; v.i = ((unsigned int)u) << 16; return v.f;
}
__device__ __forceinline__ u16 f2bf(float f) {
    union { float f; unsigned int i; } v; v.f = f;
    unsigned int r = v.i + 0x7fffu + ((v.i >> 16) & 1u);
    return (u16)(r >> 16);
}

// ---------------- f32 -> bf16 bulk convert (weights) -----------------------
__global__ __launch_bounds__(256) void cvt_bf16_k(
    const float* __restrict__ in, u16* __restrict__ out, int n)
{
    int i = blockIdx.x * 256 + threadIdx.x;
    if (i < n) out[i] = f2bf(in[i]);
}

// ---------------- LayerNorm: one block per row; f32 in, bf16 out -----------
__global__ __launch_bounds__(256) void layernorm_k(
    const float* __restrict__ x, const float* __restrict__ g,
    const float* __restrict__ b, u16* __restrict__ h)
{
    int row = blockIdx.x, tid = threadIdx.x;
    const float* xr = x + (size_t)row * D_MODEL;
    float v[3], s = 0.f, sq = 0.f;
#pragma unroll
    for (int j = 0; j < 3; ++j) {
        v[j] = xr[tid + j * 256];
        s += v[j]; sq += v[j] * v[j];
    }
#pragma unroll
    for (int off = 32; off >= 1; off >>= 1) {
        s  += __shfl_xor(s,  off, 64);
        sq += __shfl_xor(sq, off, 64);
    }
    __shared__ float sred[4], sqred[4];
    if ((tid & 63) == 0) { sred[tid >> 6] = s; sqred[tid >> 6] = sq; }
    __syncthreads();
    float st = sred[0] + sred[1] + sred[2] + sred[3];
    float sqt = sqred[0] + sqred[1] + sqred[2] + sqred[3];
    float mu = st * (1.f / D_MODEL);
    float var = sqt * (1.f / D_MODEL) - mu * mu;
    float rstd = rsqrtf(var + 1e-5f);
    u16* hr = h + (size_t)row * D_MODEL;
#pragma unroll
    for (int j = 0; j < 3; ++j) {
        int idx = tid + j * 256;
        hr[idx] = f2bf((v[j] - mu) * rstd * g[idx] + b[idx]);
    }
}

// ---------------- MFMA GEMM: C(MxN) = A(MxK) * B(NxK)^T --------------------
// 64x64 tile, BK=32, 256 threads = 4 waves; wave w owns rows [w*16,w*16+16).
// OUT_BF16: store bf16; else store f32 (optionally + f32 residual).
template<bool ADD_RES, bool OUT_BF16>
__global__ __launch_bounds__(256) void gemm_bt64(
    const u16* __restrict__ A, const u16* __restrict__ B,
    const float* __restrict__ Res, void* __restrict__ Cv,
    int M, int N, int K)
{
    __shared__ u16 As[64 * 40];   // pad to 40: 2-way LDS aliasing only (free)
    __shared__ u16 Bs[64 * 40];
    int tid = threadIdx.x;
    int wave = tid >> 6, lane = tid & 63;
    int m0 = blockIdx.x * 64, n0 = blockIdx.y * 64;
    int lrow = tid >> 2, lk = (tid & 3) * 8;
    int mloc = lane & 15, quad = lane >> 4;
    f32x4 acc[4] = {};

    const u16* aptr = A + (size_t)(m0 + lrow) * K + lk;
    const u16* bptr = B + (size_t)(n0 + lrow) * K + lk;

    for (int k0 = 0; k0 < K; k0 += 32) {
        int4 av = *(const int4*)(aptr + k0);
        int4 bv = *(const int4*)(bptr + k0);
        __syncthreads();
        *(int4*)(&As[lrow * 40 + lk]) = av;
        *(int4*)(&Bs[lrow * 40 + lk]) = bv;
        __syncthreads();
        short8 af = *(const short8*)(&As[(wave * 16 + mloc) * 40 + quad * 8]);
#pragma unroll
        for (int nt = 0; nt < 4; ++nt) {
            short8 bfr = *(const short8*)(&Bs[(nt * 16 + mloc) * 40 + quad * 8]);
            acc[nt] = __builtin_amdgcn_mfma_f32_16x16x32_bf16(af, bfr, acc[nt], 0, 0, 0);
        }
    }
    // C/D layout: col = lane&15, row = quad*4 + reg  [verified m89/m91]
#pragma unroll
    for (int nt = 0; nt < 4; ++nt) {
        int gcol = n0 + nt * 16 + mloc;
        int grow = m0 + wave * 16 + quad * 4;
#pragma unroll
        for (int r = 0; r < 4; ++r) {
            size_t idx = (size_t)(grow + r) * N + gcol;
            float v = acc[nt][r];
            if (ADD_RES) v += Res[idx];
            if (OUT_BF16) ((u16*)Cv)[idx] = f2bf(v);
            else          ((float*)Cv)[idx] = v;
        }
    }
}

// ---------------- depthwise causal conv4 + SiLU ----------------------------
__global__ __launch_bounds__(256) void conv_silu_k(
    const u16* __restrict__ xz, const float* __restrict__ cw,
    const float* __restrict__ cb, u16* __restrict__ xc)
{
    int gid = blockIdx.x * 256 + threadIdx.x;     // NROW*D_INNER
    int c = gid % D_INNER;
    int r = gid / D_INNER;
    int t = r & (SEQ - 1);
    float acc = cb[c];
#pragma unroll
    for (int k = 0; k < 4; ++k) {
        int tt = t - 3 + k;
        if (tt >= 0)
            acc += bf2f(xz[(size_t)(r - 3 + k) * D_XZ + c]) * cw[c * 4 + k];
    }
    float sig = 1.f / (1.f + __expf(-acc));
    xc[gid] = f2bf(acc * sig);
}

// ---------------- x_dbl = xc @ W_xproj^T  (N=80, K=1536) -------------------
__global__ __launch_bounds__(256) void xproj_k(
    const u16* __restrict__ xc, const float* __restrict__ W, float* __restrict__ xdbl)
{
    int gid = blockIdx.x * 256 + threadIdx.x;    // NROW*80
    int t = gid / 80, n = gid % 80;
    const u16* xr = xc + (size_t)t * D_INNER;
    const float* wr = W + (size_t)n * D_INNER;
    float acc = 0.f;
    for (int k = 0; k < D_INNER; k += 8) {
        ushort8 a = *(const ushort8*)(xr + k);
        float4 w0 = *(const float4*)(wr + k);
        float4 w1 = *(const float4*)(wr + k + 4);
        acc += bf2f(a[0]) * w0.x + bf2f(a[1]) * w0.y + bf2f(a[2]) * w0.z + bf2f(a[3]) * w0.w;
        acc += bf2f(a[4]) * w1.x + bf2f(a[5]) * w1.y + bf2f(a[6]) * w1.z + bf2f(a[7]) * w1.w;
    }
    xdbl[gid] = acc;
}

// ---------------- dt = softplus(dt_r @ W_dt^T + b_dt)  (K=48) --------------
__global__ __launch_bounds__(256) void dt_k(
    const float* __restrict__ xdbl, const float* __restrict__ W_dt,
    const float* __restrict__ b_dt, float* __restrict__ dtout)
{
    int gid = blockIdx.x * 256 + threadIdx.x;    // NROW*D_INNER
    int d = gid % D_INNER;
    int t = gid / D_INNER;
    const float* xr = xdbl + (size_t)t * 80;
    const float* wr = W_dt + (size_t)d * DT_RANK;
    float acc = b_dt[d];
#pragma unroll
    for (int k4 = 0; k4 < DT_RANK; k4 += 4) {
        float4 w = *(const float4*)(wr + k4);
        acc += xr[k4] * w.x + xr[k4 + 1] * w.y + xr[k4 + 2] * w.z + xr[k4 + 3] * w.w;
    }
    float sp = (acc > 15.f) ? acc : __logf(1.f + __expf(acc));
    dtout[gid] = sp;
}

// ---------------- sequential selective scan + fused epilogue ---------------
// thread = (b, d); 16 states in registers; yy = (y + Dp*xc) * silu(z)
__global__ __launch_bounds__(256) void scan_k(
    const float* __restrict__ dt, const u16* __restrict__ xc,
    const u16* __restrict__ xz, const float* __restrict__ xdbl,
    const float* __restrict__ A_log, const float* __restrict__ Dp,
    u16* __restrict__ yy)
{
    int b = blockIdx.x / 6;
    int d = (blockIdx.x % 6) * 256 + threadIdx.x;
    float a[D_STATE], s[D_STATE];
#pragma unroll
    for (int n = 0; n < D_STATE; ++n) {
        a[n] = -__expf(A_log[d * D_STATE + n]);
        s[n] = 0.f;
    }
    float dpv = Dp[d];
    size_t rbase = (size_t)b * SEQ;
    for (int t = 0; t < SEQ; ++t) {
        size_t r = rbase + t;
        float dtv = dt[r * D_INNER + d];
        float xcv = bf2f(xc[r * D_INNER + d]);
        float zv  = bf2f(xz[r * D_XZ + D_INNER + d]);
        const float* bc = xdbl + r * 80;
        float du = dtv * xcv;
        float y = 0.f;
#pragma unroll
        for (int n = 0; n < D_STATE; ++n) {
            float Bn = bc[DT_RANK + n];
            float Cn = bc[DT_RANK + D_STATE + n];
            s[n] = __expf(dtv * a[n]) * s[n] + du * Bn;
            y += s[n] * Cn;
        }
        float yv = y + dpv * xcv;
        float sig = 1.f / (1.f + __expf(-zv));
        yy[r * D_INNER + d] = f2bf(yv * (zv * sig));
    }
}

extern "C" void kernel_launch(void* const* d_in, const int* in_sizes, int n_in,
                              void* d_out, int out_size, void* d_ws, size_t ws_size,
                              hipStream_t stream) {
    const float* x      = (const float*)d_in[0];
    const float* ln_g   = (const float*)d_in[1];
    const float* ln_b   = (const float*)d_in[2];
    const float* W_in   = (const float*)d_in[3];
    const float* conv_w = (const float*)d_in[4];
    const float* conv_b = (const float*)d_in[5];
    const float* W_xp   = (const float*)d_in[6];
    const float* W_dt   = (const float*)d_in[7];
    const float* b_dt   = (const float*)d_in[8];
    const float* A_log  = (const float*)d_in[9];
    const float* Dp     = (const float*)d_in[10];
    const float* W_out  = (const float*)d_in[11];
    float* out = (float*)d_out;

    char* ws = (char*)d_ws;
    u16*   h_bf   = (u16*)ws;    ws += (size_t)NROW * D_MODEL * 2;     // 3.0 MB
    u16*   xz_bf  = (u16*)ws;    ws += (size_t)NROW * D_XZ * 2;        // 12.6 MB
    u16*   xc_bf  = (u16*)ws;    ws += (size_t)NROW * D_INNER * 2;     // 6.3 MB
    float* xdbl   = (float*)ws;  ws += (size_t)NROW * 80 * 4;          // 0.66 MB
    float* dtbuf  = (float*)ws;  ws += (size_t)NROW * D_INNER * 4;     // 12.6 MB
    u16*   yybuf  = (u16*)ws;    ws += (size_t)NROW * D_INNER * 2;     // 6.3 MB
    u16*   Win_bf = (u16*)ws;    ws += (size_t)D_XZ * D_MODEL * 2;     // 4.7 MB
    u16*   Wout_bf= (u16*)ws;                                          // 2.4 MB

    const int nWin  = D_XZ * D_MODEL;      // 2359296
    const int nWout = D_MODEL * D_INNER;   // 1179648
    cvt_bf16_k<<<(nWin  + 255) / 256, 256, 0, stream>>>(W_in,  Win_bf,  nWin);
    cvt_bf16_k<<<(nWout + 255) / 256, 256, 0, stream>>>(W_out, Wout_bf, nWout);

    layernorm_k<<<NROW, 256, 0, stream>>>(x, ln_g, ln_b, h_bf);
    gemm_bt64<false, true><<<dim3(NROW / 64, D_XZ / 64), 256, 0, stream>>>(
        h_bf, Win_bf, nullptr, xz_bf, NROW, D_XZ, D_MODEL);
    conv_silu_k<<<NROW * D_INNER / 256, 256, 0, stream>>>(xz_bf, conv_w, conv_b, xc_bf);
    xproj_k<<<NROW * 80 / 256, 256, 0, stream>>>(xc_bf, W_xp, xdbl);
    dt_k<<<NROW * D_INNER / 256, 256, 0, stream>>>(xdbl, W_dt, b_dt, dtbuf);
    scan_k<<<12, 256, 0, stream>>>(dtbuf, xc_bf, xz_bf, xdbl, A_log, Dp, yybuf);
    gemm_bt64<true, false><<<dim3(NROW / 64, D_MODEL / 64), 256, 0, stream>>>(
        yybuf, Wout_bf, x, out, NROW, D_MODEL, D_INNER);
}

// Round 3
// 306.585 us; speedup vs baseline: 2.9456x; 2.9456x over previous
//
#include <hip/hip_runtime.h>

typedef unsigned short u16;
typedef __attribute__((ext_vector_type(8))) short short8;
typedef __attribute__((ext_vector_type(8))) unsigned short ushort8;
typedef __attribute__((ext_vector_type(4))) float f32x4;

#define D_MODEL 768
#define D_INNER 1536
#define D_XZ    3072
#define D_STATE 16
#define DT_RANK 48
#define NROW    2048   // B*T
#define SEQ     1024
#define XDS     128    // padded x_dbl row stride (48 dt_r | 16 B | 16 C | pad)
#define NCHUNK  64
#define CLEN    16     // SEQ / NCHUNK

__device__ __forceinline__ float bf2f(u16 u) {
    union { unsigned int i; float f; } v; v.i = ((unsigned int)u) << 16; return v.f;
}
__device__ __forceinline__ u16 f2bf(float f) {
    union { float f; unsigned int i; } v; v.f = f;
    unsigned int r = v.i + 0x7fffu + ((v.i >> 16) & 1u);
    return (u16)(r >> 16);
}

// ---------------- f32 -> bf16 bulk convert (weights) -----------------------
__global__ __launch_bounds__(256) void cvt_bf16_k(
    const float* __restrict__ in, u16* __restrict__ out, int n)
{
    int i = blockIdx.x * 256 + threadIdx.x;
    if (i < n) out[i] = f2bf(in[i]);
}

// convert with zero-pad tail (for W_xproj padded to 128 rows)
__global__ __launch_bounds__(256) void cvt_pad_k(
    const float* __restrict__ in, u16* __restrict__ out, int n_valid, int n_total)
{
    int i = blockIdx.x * 256 + threadIdx.x;
    if (i < n_total) out[i] = (i < n_valid) ? f2bf(in[i]) : (u16)0;
}

// ---------------- LayerNorm: one block per row; f32 in, bf16 out -----------
__global__ __launch_bounds__(256) void layernorm_k(
    const float* __restrict__ x, const float* __restrict__ g,
    const float* __restrict__ b, u16* __restrict__ h)
{
    int row = blockIdx.x, tid = threadIdx.x;
    const float* xr = x + (size_t)row * D_MODEL;
    float v[3], s = 0.f, sq = 0.f;
#pragma unroll
    for (int j = 0; j < 3; ++j) {
        v[j] = xr[tid + j * 256];
        s += v[j]; sq += v[j] * v[j];
    }
#pragma unroll
    for (int off = 32; off >= 1; off >>= 1) {
        s  += __shfl_xor(s,  off, 64);
        sq += __shfl_xor(sq, off, 64);
    }
    __shared__ float sred[4], sqred[4];
    if ((tid & 63) == 0) { sred[tid >> 6] = s; sqred[tid >> 6] = sq; }
    __syncthreads();
    float st = sred[0] + sred[1] + sred[2] + sred[3];
    float sqt = sqred[0] + sqred[1] + sqred[2] + sqred[3];
    float mu = st * (1.f / D_MODEL);
    float var = sqt * (1.f / D_MODEL) - mu * mu;
    float rstd = rsqrtf(var + 1e-5f);
    u16* hr = h + (size_t)row * D_MODEL;
#pragma unroll
    for (int j = 0; j < 3; ++j) {
        int idx = tid + j * 256;
        hr[idx] = f2bf((v[j] - mu) * rstd * g[idx] + b[idx]);
    }
}

// ---------------- MFMA GEMM: C(MxN) = A(MxK) * B(NxK)^T --------------------
// 64x64 tile, BK=32, 256 threads = 4 waves; wave w owns rows [w*16,w*16+16).
// OUT_BF16: store bf16; else store f32 (optionally + f32 residual).
// CSTRIDE: row stride of C (and Res) in elements.
template<bool ADD_RES, bool OUT_BF16>
__global__ __launch_bounds__(256) void gemm_bt64(
    const u16* __restrict__ A, const u16* __restrict__ B,
    const float* __restrict__ Res, void* __restrict__ Cv,
    int M, int N, int K, int CSTRIDE)
{
    __shared__ u16 As[64 * 40];   // pad to 40: 2-way LDS aliasing only (free)
    __shared__ u16 Bs[64 * 40];
    int tid = threadIdx.x;
    int wave = tid >> 6, lane = tid & 63;
    int m0 = blockIdx.x * 64, n0 = blockIdx.y * 64;
    int lrow = tid >> 2, lk = (tid & 3) * 8;
    int mloc = lane & 15, quad = lane >> 4;
    f32x4 acc[4] = {};

    const u16* aptr = A + (size_t)(m0 + lrow) * K + lk;
    const u16* bptr = B + (size_t)(n0 + lrow) * K + lk;

    for (int k0 = 0; k0 < K; k0 += 32) {
        int4 av = *(const int4*)(aptr + k0);
        int4 bv = *(const int4*)(bptr + k0);
        __syncthreads();
        *(int4*)(&As[lrow * 40 + lk]) = av;
        *(int4*)(&Bs[lrow * 40 + lk]) = bv;
        __syncthreads();
        short8 af = *(const short8*)(&As[(wave * 16 + mloc) * 40 + quad * 8]);
#pragma unroll
        for (int nt = 0; nt < 4; ++nt) {
            short8 bfr = *(const short8*)(&Bs[(nt * 16 + mloc) * 40 + quad * 8]);
            acc[nt] = __builtin_amdgcn_mfma_f32_16x16x32_bf16(af, bfr, acc[nt], 0, 0, 0);
        }
    }
    // C/D layout: col = lane&15, row = quad*4 + reg  [verified m89/m91]
#pragma unroll
    for (int nt = 0; nt < 4; ++nt) {
        int gcol = n0 + nt * 16 + mloc;
        int grow = m0 + wave * 16 + quad * 4;
#pragma unroll
        for (int r = 0; r < 4; ++r) {
            size_t idx = (size_t)(grow + r) * CSTRIDE + gcol;
            float v = acc[nt][r];
            if (ADD_RES) v += Res[idx];
            if (OUT_BF16) ((u16*)Cv)[idx] = f2bf(v);
            else          ((float*)Cv)[idx] = v;
        }
    }
}

// ---------------- depthwise causal conv4 + SiLU ----------------------------
__global__ __launch_bounds__(256) void conv_silu_k(
    const u16* __restrict__ xz, const float* __restrict__ cw,
    const float* __restrict__ cb, u16* __restrict__ xc)
{
    int gid = blockIdx.x * 256 + threadIdx.x;     // NROW*D_INNER
    int c = gid % D_INNER;
    int r = gid / D_INNER;
    int t = r & (SEQ - 1);
    float acc = cb[c];
#pragma unroll
    for (int k = 0; k < 4; ++k) {
        int tt = t - 3 + k;
        if (tt >= 0)
            acc += bf2f(xz[(size_t)(r - 3 + k) * D_XZ + c]) * cw[c * 4 + k];
    }
    float sig = 1.f / (1.f + __expf(-acc));
    xc[gid] = f2bf(acc * sig);
}

// ---------------- dt = softplus(dt_r @ W_dt^T + b_dt)  (K=48) --------------
__global__ __launch_bounds__(256) void dt_k(
    const float* __restrict__ xdbl, const float* __restrict__ W_dt,
    const float* __restrict__ b_dt, float* __restrict__ dtout)
{
    int gid = blockIdx.x * 256 + threadIdx.x;    // NROW*D_INNER
    int d = gid % D_INNER;
    int t = gid / D_INNER;
    const float* xr = xdbl + (size_t)t * XDS;
    const float* wr = W_dt + (size_t)d * DT_RANK;
    float acc = b_dt[d];
#pragma unroll
    for (int k4 = 0; k4 < DT_RANK; k4 += 4) {
        float4 w = *(const float4*)(wr + k4);
        acc += xr[k4] * w.x + xr[k4 + 1] * w.y + xr[k4 + 2] * w.z + xr[k4 + 3] * w.w;
    }
    float sp = (acc > 15.f) ? acc : __logf(1.f + __expf(acc));
    dtout[gid] = sp;
}

// ================= chunked parallel scan ===================================
// P1: thread=(b,c,d) scans CLEN steps from s=0 -> S[16], dtsum.
__global__ __launch_bounds__(256) void scan_p1(
    const float* __restrict__ dt, const u16* __restrict__ xc,
    const float* __restrict__ xdbl, const float* __restrict__ A_log,
    float* __restrict__ Sbuf, float* __restrict__ dtsumbuf)
{
    int gid = blockIdx.x * 256 + threadIdx.x;   // B*NCHUNK*D_INNER
    int d = gid % D_INNER;
    int bcN = gid / D_INNER;        // b*NCHUNK + c
    int c = bcN % NCHUNK;
    int b = bcN / NCHUNK;
    float a[D_STATE], s[D_STATE];
#pragma unroll
    for (int n = 0; n < D_STATE; ++n) {
        a[n] = -__expf(A_log[d * D_STATE + n]);
        s[n] = 0.f;
    }
    float dtsum = 0.f;
    size_t r0 = (size_t)b * SEQ + c * CLEN;
    for (int t = 0; t < CLEN; ++t) {
        size_t r = r0 + t;
        float dtv = dt[r * D_INNER + d];
        float du = dtv * bf2f(xc[r * D_INNER + d]);
        dtsum += dtv;
        const float* row = xdbl + r * XDS + DT_RANK;
        float4 B0 = *(const float4*)(row);
        float4 B1 = *(const float4*)(row + 4);
        float4 B2 = *(const float4*)(row + 8);
        float4 B3 = *(const float4*)(row + 12);
        float Bv[16] = {B0.x,B0.y,B0.z,B0.w,B1.x,B1.y,B1.z,B1.w,
                        B2.x,B2.y,B2.z,B2.w,B3.x,B3.y,B3.z,B3.w};
#pragma unroll
        for (int n = 0; n < D_STATE; ++n)
            s[n] = __expf(dtv * a[n]) * s[n] + du * Bv[n];
    }
    float4* So = (float4*)(Sbuf + (size_t)gid * D_STATE);
#pragma unroll
    for (int j = 0; j < 4; ++j)
        So[j] = make_float4(s[j*4], s[j*4+1], s[j*4+2], s[j*4+3]);
    dtsumbuf[gid] = dtsum;
}

// P2: thread=(b,d,n) combines NCHUNK chunks sequentially, writes carry-in.
__global__ __launch_bounds__(256) void scan_p2(
    const float* __restrict__ Sbuf, const float* __restrict__ dtsumbuf,
    const float* __restrict__ A_log, float* __restrict__ carry)
{
    int gid = blockIdx.x * 256 + threadIdx.x;   // B*D_INNER*16
    int n = gid % D_STATE;
    int d = (gid / D_STATE) % D_INNER;
    int b = gid / (D_STATE * D_INNER);
    float a = -__expf(A_log[d * D_STATE + n]);
    float s = 0.f;
    for (int c = 0; c < NCHUNK; ++c) {
        size_t idx = ((size_t)(b * NCHUNK + c) * D_INNER + d);
        carry[idx * D_STATE + n] = s;
        s = Sbuf[idx * D_STATE + n] + __expf(a * dtsumbuf[idx]) * s;
    }
}

// P3: thread=(b,c,d), seeded with carry; emits yy = (y + Dp*xc)*silu(z).
__global__ __launch_bounds__(256) void scan_p3(
    const float* __restrict__ dt, const u16* __restrict__ xc,
    const u16* __restrict__ xz, const float* __restrict__ xdbl,
    const float* __restrict__ A_log, const float* __restrict__ Dp,
    const float* __restrict__ carry, u16* __restrict__ yy)
{
    int gid = blockIdx.x * 256 + threadIdx.x;   // B*NCHUNK*D_INNER
    int d = gid % D_INNER;
    int bcN = gid / D_INNER;
    int c = bcN % NCHUNK;
    int b = bcN / NCHUNK;
    float a[D_STATE], s[D_STATE];
    const float4* Ci = (const float4*)(carry + (size_t)gid * D_STATE);
    float4 c0 = Ci[0], c1 = Ci[1], c2 = Ci[2], c3 = Ci[3];
    s[0]=c0.x; s[1]=c0.y; s[2]=c0.z; s[3]=c0.w;
    s[4]=c1.x; s[5]=c1.y; s[6]=c1.z; s[7]=c1.w;
    s[8]=c2.x; s[9]=c2.y; s[10]=c2.z; s[11]=c2.w;
    s[12]=c3.x; s[13]=c3.y; s[14]=c3.z; s[15]=c3.w;
#pragma unroll
    for (int n = 0; n < D_STATE; ++n)
        a[n] = -__expf(A_log[d * D_STATE + n]);
    float dpv = Dp[d];
    size_t r0 = (size_t)b * SEQ + c * CLEN;
    for (int t = 0; t < CLEN; ++t) {
        size_t r = r0 + t;
        float dtv = dt[r * D_INNER + d];
        float xcv = bf2f(xc[r * D_INNER + d]);
        float zv  = bf2f(xz[r * D_XZ + D_INNER + d]);
        float du = dtv * xcv;
        const float* row = xdbl + r * XDS + DT_RANK;
        float4 B0 = *(const float4*)(row);
        float4 B1 = *(const float4*)(row + 4);
        float4 B2 = *(const float4*)(row + 8);
        float4 B3 = *(const float4*)(row + 12);
        float4 C0 = *(const float4*)(row + 16);
        float4 C1 = *(const float4*)(row + 20);
        float4 C2 = *(const float4*)(row + 24);
        float4 C3 = *(const float4*)(row + 28);
        float Bv[16] = {B0.x,B0.y,B0.z,B0.w,B1.x,B1.y,B1.z,B1.w,
                        B2.x,B2.y,B2.z,B2.w,B3.x,B3.y,B3.z,B3.w};
        float Cv[16] = {C0.x,C0.y,C0.z,C0.w,C1.x,C1.y,C1.z,C1.w,
                        C2.x,C2.y,C2.z,C2.w,C3.x,C3.y,C3.z,C3.w};
        float y = 0.f;
#pragma unroll
        for (int n = 0; n < D_STATE; ++n) {
            s[n] = __expf(dtv * a[n]) * s[n] + du * Bv[n];
            y += s[n] * Cv[n];
        }
        float yv = y + dpv * xcv;
        float sig = 1.f / (1.f + __expf(-zv));
        yy[r * D_INNER + d] = f2bf(yv * (zv * sig));
    }
}

extern "C" void kernel_launch(void* const* d_in, const int* in_sizes, int n_in,
                              void* d_out, int out_size, void* d_ws, size_t ws_size,
                              hipStream_t stream) {
    const float* x      = (const float*)d_in[0];
    const float* ln_g   = (const float*)d_in[1];
    const float* ln_b   = (const float*)d_in[2];
    const float* W_in   = (const float*)d_in[3];
    const float* conv_w = (const float*)d_in[4];
    const float* conv_b = (const float*)d_in[5];
    const float* W_xp   = (const float*)d_in[6];
    const float* W_dt   = (const float*)d_in[7];
    const float* b_dt   = (const float*)d_in[8];
    const float* A_log  = (const float*)d_in[9];
    const float* Dp     = (const float*)d_in[10];
    const float* W_out  = (const float*)d_in[11];
    float* out = (float*)d_out;

    char* ws = (char*)d_ws;
    u16*   h_bf    = (u16*)ws;   ws += (size_t)NROW * D_MODEL * 2;           // 3.0 MB
    u16*   xz_bf   = (u16*)ws;   ws += (size_t)NROW * D_XZ * 2;              // 12.6 MB
    u16*   xc_bf   = (u16*)ws;   ws += (size_t)NROW * D_INNER * 2;           // 6.3 MB
    float* xdbl    = (float*)ws; ws += (size_t)NROW * XDS * 4;               // 1.0 MB
    float* dtbuf   = (float*)ws; ws += (size_t)NROW * D_INNER * 4;           // 12.6 MB
    u16*   yybuf   = (u16*)ws;   ws += (size_t)NROW * D_INNER * 2;           // 6.3 MB
    u16*   Win_bf  = (u16*)ws;   ws += (size_t)D_XZ * D_MODEL * 2;           // 4.7 MB
    u16*   Wout_bf = (u16*)ws;   ws += (size_t)D_MODEL * D_INNER * 2;        // 2.4 MB
    u16*   Wxp_bf  = (u16*)ws;   ws += (size_t)XDS * D_INNER * 2;            // 0.4 MB
    float* Sbuf    = (float*)ws; ws += (size_t)2 * NCHUNK * D_INNER * 16 * 4;// 12.6 MB
    float* dtsumb  = (float*)ws; ws += (size_t)2 * NCHUNK * D_INNER * 4;     // 0.8 MB
    float* carryb  = (float*)ws;                                             // 12.6 MB

    const int nWin  = D_XZ * D_MODEL;
    const int nWout = D_MODEL * D_INNER;
    cvt_bf16_k<<<(nWin  + 255) / 256, 256, 0, stream>>>(W_in,  Win_bf,  nWin);
    cvt_bf16_k<<<(nWout + 255) / 256, 256, 0, stream>>>(W_out, Wout_bf, nWout);
    cvt_pad_k<<<(XDS * D_INNER + 255) / 256, 256, 0, stream>>>(
        W_xp, Wxp_bf, 80 * D_INNER, XDS * D_INNER);

    layernorm_k<<<NROW, 256, 0, stream>>>(x, ln_g, ln_b, h_bf);
    gemm_bt64<false, true><<<dim3(NROW / 64, D_XZ / 64), 256, 0, stream>>>(
        h_bf, Win_bf, nullptr, xz_bf, NROW, D_XZ, D_MODEL, D_XZ);
    conv_silu_k<<<NROW * D_INNER / 256, 256, 0, stream>>>(xz_bf, conv_w, conv_b, xc_bf);
    gemm_bt64<false, false><<<dim3(NROW / 64, XDS / 64), 256, 0, stream>>>(
        xc_bf, Wxp_bf, nullptr, xdbl, NROW, XDS, D_INNER, XDS);
    dt_k<<<NROW * D_INNER / 256, 256, 0, stream>>>(xdbl, W_dt, b_dt, dtbuf);

    scan_p1<<<2 * NCHUNK * D_INNER / 256, 256, 0, stream>>>(
        dtbuf, xc_bf, xdbl, A_log, Sbuf, dtsumb);
    scan_p2<<<2 * D_INNER * D_STATE / 256, 256, 0, stream>>>(
        Sbuf, dtsumb, A_log, carryb);
    scan_p3<<<2 * NCHUNK * D_INNER / 256, 256, 0, stream>>>(
        dtbuf, xc_bf, xz_bf, xdbl, A_log, Dp, carryb, yybuf);

    gemm_bt64<true, false><<<dim3(NROW / 64, D_MODEL / 64), 256, 0, stream>>>(
        yybuf, Wout_bf, x, out, NROW, D_MODEL, D_INNER, D_MODEL);
}

// Round 4
// 244.670 us; speedup vs baseline: 3.6910x; 1.2531x over previous
//
#include <hip/hip_runtime.h>

typedef unsigned short u16;
typedef unsigned int u32;
typedef __attribute__((ext_vector_type(8))) short short8;
typedef __attribute__((ext_vector_type(4))) float f32x4;

#define D_MODEL 768
#define D_INNER 1536
#define D_XZ    3072
#define D_STATE 16
#define DT_RANK 48
#define NROW    2048   // B*T
#define SEQ     1024
#define XDS     128    // padded x_dbl row stride (48 dt_r | 16 B | 16 C | pad)
#define NCHUNK  64
#define CLEN    16     // SEQ / NCHUNK

typedef const __attribute__((address_space(1))) u32 glb_u32;
typedef __attribute__((address_space(3))) u32 lds_u32;

__device__ __forceinline__ float bf2f(u16 u) {
    union { unsigned int i; float f; } v; v.i = ((unsigned int)u) << 16; return v.f;
}
__device__ __forceinline__ u16 f2bf(float f) {
    union { float f; unsigned int i; } v; v.f = f;
    unsigned int r = v.i + 0x7fffu + ((v.i >> 16) & 1u);
    return (u16)(r >> 16);
}
// async global->LDS, 16B per lane; lds dest is wave-uniform base + lane*16
__device__ __forceinline__ void g2lds16(const u16* g, u16* l) {
    __builtin_amdgcn_global_load_lds((glb_u32*)g, (lds_u32*)l, 16, 0, 0);
}

// ---------------- f32 -> bf16 bulk convert (x4 vectorized) -----------------
__global__ __launch_bounds__(256) void cvt_bf16_k(
    const float* __restrict__ in, u16* __restrict__ out, int n4)
{
    int i = blockIdx.x * 256 + threadIdx.x;
    if (i < n4) {
        float4 v = *(const float4*)(in + i * 4);
        u16* o = out + i * 4;
        o[0] = f2bf(v.x); o[1] = f2bf(v.y); o[2] = f2bf(v.z); o[3] = f2bf(v.w);
    }
}

// convert with zero-pad tail (flat): W_xproj padded to 128 rows
__global__ __launch_bounds__(256) void cvt_pad_k(
    const float* __restrict__ in, u16* __restrict__ out, int n_valid, int n_total)
{
    int i = blockIdx.x * 256 + threadIdx.x;
    if (i < n_total) out[i] = (i < n_valid) ? f2bf(in[i]) : (u16)0;
}

// 2D pad convert: W_dt (1536x48) -> bf16 (1536x64), cols 48..63 = 0
__global__ __launch_bounds__(256) void cvt_pad2d_k(
    const float* __restrict__ in, u16* __restrict__ out, int rows)
{
    int i = blockIdx.x * 256 + threadIdx.x;
    if (i >= rows * 64) return;
    int r = i >> 6, c = i & 63;
    out[i] = (c < DT_RANK) ? f2bf(in[r * DT_RANK + c]) : (u16)0;
}

// ---------------- LayerNorm: one block per row; f32 in, bf16 out -----------
__global__ __launch_bounds__(256) void layernorm_k(
    const float* __restrict__ x, const float* __restrict__ g,
    const float* __restrict__ b, u16* __restrict__ h)
{
    int row = blockIdx.x, tid = threadIdx.x;
    const float* xr = x + (size_t)row * D_MODEL;
    float v[3], s = 0.f, sq = 0.f;
#pragma unroll
    for (int j = 0; j < 3; ++j) {
        v[j] = xr[tid + j * 256];
        s += v[j]; sq += v[j] * v[j];
    }
#pragma unroll
    for (int off = 32; off >= 1; off >>= 1) {
        s  += __shfl_xor(s,  off, 64);
        sq += __shfl_xor(sq, off, 64);
    }
    __shared__ float sred[4], sqred[4];
    if ((tid & 63) == 0) { sred[tid >> 6] = s; sqred[tid >> 6] = sq; }
    __syncthreads();
    float st = sred[0] + sred[1] + sred[2] + sred[3];
    float sqt = sqred[0] + sqred[1] + sqred[2] + sqred[3];
    float mu = st * (1.f / D_MODEL);
    float var = sqt * (1.f / D_MODEL) - mu * mu;
    float rstd = rsqrtf(var + 1e-5f);
    u16* hr = h + (size_t)row * D_MODEL;
#pragma unroll
    for (int j = 0; j < 3; ++j) {
        int idx = tid + j * 256;
        hr[idx] = f2bf((v[j] - mu) * rstd * g[idx] + b[idx]);
    }
}

// ============ m97-style MFMA GEMM: C(MxN) = A(MxK) * B(NxK)^T ==============
// Block = 4 waves in 2x2; wave tile = (MT*16) x (NT*16); BM=32*MT, BN=32*NT.
// global_load_lds width-16 staging into unpadded LDS with XOR colblock
// swizzle  cb ^= (row>>1)&3  (caps b128 read aliasing at 2-way = free).
template<int MT, int NT, bool OUT_BF16, bool ADD_RES>
__global__ __launch_bounds__(256) void gemm128(
    const u16* __restrict__ A, const u16* __restrict__ B,
    const float* __restrict__ Res, void* __restrict__ Cv,
    int M, int N, int K)
{
    constexpr int BM = 32 * MT, BN = 32 * NT;
    __shared__ __align__(16) u16 As[BM * 32];
    __shared__ __align__(16) u16 Bs[BN * 32];
    int tid = threadIdx.x, w = tid >> 6, lane = tid & 63;
    int wm = w & 1, wn = w >> 1;
    int m0 = blockIdx.x * BM, n0 = blockIdx.y * BN;
    int mloc = lane & 15, quad = lane >> 4;
    int lr = lane >> 2, lc = lane & 3;
    f32x4 acc[MT][NT] = {};

    for (int k0 = 0; k0 < K; k0 += 32) {
        __syncthreads();   // all waves done reading LDS from previous iter
#pragma unroll
        for (int j = w; j < 2 * MT; j += 4) {
            int row = j * 16 + lr;
            int cb = lc ^ ((row >> 1) & 3);
            g2lds16(A + (size_t)(m0 + row) * K + k0 + cb * 8, &As[j * 512]);
        }
#pragma unroll
        for (int j = w; j < 2 * NT; j += 4) {
            int row = j * 16 + lr;
            int cb = lc ^ ((row >> 1) & 3);
            g2lds16(B + (size_t)(n0 + row) * K + k0 + cb * 8, &Bs[j * 512]);
        }
        __syncthreads();   // drains vmcnt(0) before barrier (compiler-inserted)
        short8 afr[MT], bfr[NT];
#pragma unroll
        for (int mt = 0; mt < MT; ++mt) {
            int row = wm * MT * 16 + mt * 16 + mloc;
            int cb = quad ^ ((row >> 1) & 3);
            afr[mt] = *(const short8*)(&As[row * 32 + cb * 8]);
        }
#pragma unroll
        for (int nt = 0; nt < NT; ++nt) {
            int row = wn * NT * 16 + nt * 16 + mloc;
            int cb = quad ^ ((row >> 1) & 3);
            bfr[nt] = *(const short8*)(&Bs[row * 32 + cb * 8]);
        }
#pragma unroll
        for (int mt = 0; mt < MT; ++mt)
#pragma unroll
            for (int nt = 0; nt < NT; ++nt)
                acc[mt][nt] = __builtin_amdgcn_mfma_f32_16x16x32_bf16(
                    afr[mt], bfr[nt], acc[mt][nt], 0, 0, 0);
    }
    // C/D layout: col = lane&15, row = quad*4 + reg  [verified m89/m91]
#pragma unroll
    for (int mt = 0; mt < MT; ++mt) {
        int grow0 = m0 + wm * MT * 16 + mt * 16 + quad * 4;
#pragma unroll
        for (int nt = 0; nt < NT; ++nt) {
            int gcol = n0 + wn * NT * 16 + nt * 16 + mloc;
#pragma unroll
            for (int r = 0; r < 4; ++r) {
                size_t idx = (size_t)(grow0 + r) * N + gcol;
                float v = acc[mt][nt][r];
                if (ADD_RES) v += Res[idx];
                if (OUT_BF16) ((u16*)Cv)[idx] = f2bf(v);
                else          ((float*)Cv)[idx] = v;
            }
        }
    }
}

// ---------------- 64x64 MFMA GEMM with custom epilogues --------------------
// EPI 0: f32 out (stride CSTRIDE) + bf16 dt_r extraction (cols 0..63, n0==0)
// EPI 1: f32 out = softplus(acc + bias[gcol])
template<int EPI>
__global__ __launch_bounds__(256) void gemm_bt64(
    const u16* __restrict__ A, const u16* __restrict__ B,
    const float* __restrict__ bias, void* __restrict__ Cv,
    int M, int N, int K, int CSTRIDE, u16* __restrict__ dtr)
{
    __shared__ __align__(16) u16 As[64 * 40];
    __shared__ __align__(16) u16 Bs[64 * 40];
    int tid = threadIdx.x;
    int wave = tid >> 6, lane = tid & 63;
    int m0 = blockIdx.x * 64, n0 = blockIdx.y * 64;
    int lrow = tid >> 2, lk = (tid & 3) * 8;
    int mloc = lane & 15, quad = lane >> 4;
    f32x4 acc[4] = {};

    const u16* aptr = A + (size_t)(m0 + lrow) * K + lk;
    const u16* bptr = B + (size_t)(n0 + lrow) * K + lk;

    for (int k0 = 0; k0 < K; k0 += 32) {
        int4 av = *(const int4*)(aptr + k0);
        int4 bv = *(const int4*)(bptr + k0);
        __syncthreads();
        *(int4*)(&As[lrow * 40 + lk]) = av;
        *(int4*)(&Bs[lrow * 40 + lk]) = bv;
        __syncthreads();
        short8 af = *(const short8*)(&As[(wave * 16 + mloc) * 40 + quad * 8]);
#pragma unroll
        for (int nt = 0; nt < 4; ++nt) {
            short8 bfr = *(const short8*)(&Bs[(nt * 16 + mloc) * 40 + quad * 8]);
            acc[nt] = __builtin_amdgcn_mfma_f32_16x16x32_bf16(af, bfr, acc[nt], 0, 0, 0);
        }
    }
#pragma unroll
    for (int nt = 0; nt < 4; ++nt) {
        int gcol = n0 + nt * 16 + mloc;
        int grow = m0 + wave * 16 + quad * 4;
#pragma unroll
        for (int r = 0; r < 4; ++r) {
            size_t idx = (size_t)(grow + r) * CSTRIDE + gcol;
            float v = acc[nt][r];
            if (EPI == 0) {
                ((float*)Cv)[idx] = v;
                if (n0 == 0)   // dt_r bf16 extraction, zero-padded past DT_RANK
                    dtr[(size_t)(grow + r) * 64 + gcol] =
                        (gcol < DT_RANK) ? f2bf(v) : (u16)0;
            } else {           // bias + softplus
                float t = v + bias[gcol];
                float sp = (t > 15.f) ? t : __logf(1.f + __expf(t));
                ((float*)Cv)[idx] = sp;
            }
        }
    }
}

// ---------------- depthwise causal conv4 + SiLU ----------------------------
__global__ __launch_bounds__(256) void conv_silu_k(
    const u16* __restrict__ xz, const float* __restrict__ cw,
    const float* __restrict__ cb, u16* __restrict__ xc)
{
    int gid = blockIdx.x * 256 + threadIdx.x;     // NROW*D_INNER
    int c = gid % D_INNER;
    int r = gid / D_INNER;
    int t = r & (SEQ - 1);
    float acc = cb[c];
#pragma unroll
    for (int k = 0; k < 4; ++k) {
        int tt = t - 3 + k;
        if (tt >= 0)
            acc += bf2f(xz[(size_t)(r - 3 + k) * D_XZ + c]) * cw[c * 4 + k];
    }
    float sig = 1.f / (1.f + __expf(-acc));
    xc[gid] = f2bf(acc * sig);
}

// ================= chunked parallel scan ===================================
__global__ __launch_bounds__(256) void scan_p1(
    const float* __restrict__ dt, const u16* __restrict__ xc,
    const float* __restrict__ xdbl, const float* __restrict__ A_log,
    float* __restrict__ Sbuf, float* __restrict__ dtsumbuf)
{
    int gid = blockIdx.x * 256 + threadIdx.x;   // B*NCHUNK*D_INNER
    int d = gid % D_INNER;
    int bcN = gid / D_INNER;
    int c = bcN % NCHUNK;
    int b = bcN / NCHUNK;
    float a[D_STATE], s[D_STATE];
#pragma unroll
    for (int n = 0; n < D_STATE; ++n) {
        a[n] = -__expf(A_log[d * D_STATE + n]);
        s[n] = 0.f;
    }
    float dtsum = 0.f;
    size_t r0 = (size_t)b * SEQ + c * CLEN;
    for (int t = 0; t < CLEN; ++t) {
        size_t r = r0 + t;
        float dtv = dt[r * D_INNER + d];
        float du = dtv * bf2f(xc[r * D_INNER + d]);
        dtsum += dtv;
        const float* row = xdbl + r * XDS + DT_RANK;
        float4 B0 = *(const float4*)(row);
        float4 B1 = *(const float4*)(row + 4);
        float4 B2 = *(const float4*)(row + 8);
        float4 B3 = *(const float4*)(row + 12);
        float Bv[16] = {B0.x,B0.y,B0.z,B0.w,B1.x,B1.y,B1.z,B1.w,
                        B2.x,B2.y,B2.z,B2.w,B3.x,B3.y,B3.z,B3.w};
#pragma unroll
        for (int n = 0; n < D_STATE; ++n)
            s[n] = __expf(dtv * a[n]) * s[n] + du * Bv[n];
    }
    float4* So = (float4*)(Sbuf + (size_t)gid * D_STATE);
#pragma unroll
    for (int j = 0; j < 4; ++j)
        So[j] = make_float4(s[j*4], s[j*4+1], s[j*4+2], s[j*4+3]);
    dtsumbuf[gid] = dtsum;
}

__global__ __launch_bounds__(256) void scan_p2(
    const float* __restrict__ Sbuf, const float* __restrict__ dtsumbuf,
    const float* __restrict__ A_log, float* __restrict__ carry)
{
    int gid = blockIdx.x * 256 + threadIdx.x;   // B*D_INNER*16
    int n = gid % D_STATE;
    int d = (gid / D_STATE) % D_INNER;
    int b = gid / (D_STATE * D_INNER);
    float a = -__expf(A_log[d * D_STATE + n]);
    float s = 0.f;
    for (int c = 0; c < NCHUNK; ++c) {
        size_t idx = ((size_t)(b * NCHUNK + c) * D_INNER + d);
        carry[idx * D_STATE + n] = s;
        s = Sbuf[idx * D_STATE + n] + __expf(a * dtsumbuf[idx]) * s;
    }
}

__global__ __launch_bounds__(256) void scan_p3(
    const float* __restrict__ dt, const u16* __restrict__ xc,
    const u16* __restrict__ xz, const float* __restrict__ xdbl,
    const float* __restrict__ A_log, const float* __restrict__ Dp,
    const float* __restrict__ carry, u16* __restrict__ yy)
{
    int gid = blockIdx.x * 256 + threadIdx.x;   // B*NCHUNK*D_INNER
    int d = gid % D_INNER;
    int bcN = gid / D_INNER;
    int c = bcN % NCHUNK;
    int b = bcN / NCHUNK;
    float a[D_STATE], s[D_STATE];
    const float4* Ci = (const float4*)(carry + (size_t)gid * D_STATE);
    float4 c0 = Ci[0], c1 = Ci[1], c2 = Ci[2], c3 = Ci[3];
    s[0]=c0.x; s[1]=c0.y; s[2]=c0.z; s[3]=c0.w;
    s[4]=c1.x; s[5]=c1.y; s[6]=c1.z; s[7]=c1.w;
    s[8]=c2.x; s[9]=c2.y; s[10]=c2.z; s[11]=c2.w;
    s[12]=c3.x; s[13]=c3.y; s[14]=c3.z; s[15]=c3.w;
#pragma unroll
    for (int n = 0; n < D_STATE; ++n)
        a[n] = -__expf(A_log[d * D_STATE + n]);
    float dpv = Dp[d];
    size_t r0 = (size_t)b * SEQ + c * CLEN;
    for (int t = 0; t < CLEN; ++t) {
        size_t r = r0 + t;
        float dtv = dt[r * D_INNER + d];
        float xcv = bf2f(xc[r * D_INNER + d]);
        float zv  = bf2f(xz[r * D_XZ + D_INNER + d]);
        float du = dtv * xcv;
        const float* row = xdbl + r * XDS + DT_RANK;
        float4 B0 = *(const float4*)(row);
        float4 B1 = *(const float4*)(row + 4);
        float4 B2 = *(const float4*)(row + 8);
        float4 B3 = *(const float4*)(row + 12);
        float4 C0 = *(const float4*)(row + 16);
        float4 C1 = *(const float4*)(row + 20);
        float4 C2 = *(const float4*)(row + 24);
        float4 C3 = *(const float4*)(row + 28);
        float Bv[16] = {B0.x,B0.y,B0.z,B0.w,B1.x,B1.y,B1.z,B1.w,
                        B2.x,B2.y,B2.z,B2.w,B3.x,B3.y,B3.z,B3.w};
        float Cv[16] = {C0.x,C0.y,C0.z,C0.w,C1.x,C1.y,C1.z,C1.w,
                        C2.x,C2.y,C2.z,C2.w,C3.x,C3.y,C3.z,C3.w};
        float y = 0.f;
#pragma unroll
        for (int n = 0; n < D_STATE; ++n) {
            s[n] = __expf(dtv * a[n]) * s[n] + du * Bv[n];
            y += s[n] * Cv[n];
        }
        float yv = y + dpv * xcv;
        float sig = 1.f / (1.f + __expf(-zv));
        yy[r * D_INNER + d] = f2bf(yv * (zv * sig));
    }
}

extern "C" void kernel_launch(void* const* d_in, const int* in_sizes, int n_in,
                              void* d_out, int out_size, void* d_ws, size_t ws_size,
                              hipStream_t stream) {
    const float* x      = (const float*)d_in[0];
    const float* ln_g   = (const float*)d_in[1];
    const float* ln_b   = (const float*)d_in[2];
    const float* W_in   = (const float*)d_in[3];
    const float* conv_w = (const float*)d_in[4];
    const float* conv_b = (const float*)d_in[5];
    const float* W_xp   = (const float*)d_in[6];
    const float* W_dt   = (const float*)d_in[7];
    const float* b_dt   = (const float*)d_in[8];
    const float* A_log  = (const float*)d_in[9];
    const float* Dp     = (const float*)d_in[10];
    const float* W_out  = (const float*)d_in[11];
    float* out = (float*)d_out;

    char* ws = (char*)d_ws;
    u16*   h_bf    = (u16*)ws;   ws += (size_t)NROW * D_MODEL * 2;           // 3.0 MB
    u16*   xz_bf   = (u16*)ws;   ws += (size_t)NROW * D_XZ * 2;              // 12.6 MB
    u16*   xc_bf   = (u16*)ws;   ws += (size_t)NROW * D_INNER * 2;           // 6.3 MB
    float* xdbl    = (float*)ws; ws += (size_t)NROW * XDS * 4;               // 1.0 MB
    float* dtbuf   = (float*)ws; ws += (size_t)NROW * D_INNER * 4;           // 12.6 MB
    u16*   yybuf   = (u16*)ws;   ws += (size_t)NROW * D_INNER * 2;           // 6.3 MB
    u16*   Win_bf  = (u16*)ws;   ws += (size_t)D_XZ * D_MODEL * 2;           // 4.7 MB
    u16*   Wout_bf = (u16*)ws;   ws += (size_t)D_MODEL * D_INNER * 2;        // 2.4 MB
    u16*   Wxp_bf  = (u16*)ws;   ws += (size_t)XDS * D_INNER * 2;            // 0.4 MB
    u16*   dtr_bf  = (u16*)ws;   ws += (size_t)NROW * 64 * 2;                // 0.25 MB
    u16*   Wdt_bf  = (u16*)ws;   ws += (size_t)D_INNER * 64 * 2;             // 0.2 MB
    float* Sbuf    = (float*)ws; ws += (size_t)2 * NCHUNK * D_INNER * 16 * 4;// 12.6 MB
    float* dtsumb  = (float*)ws; ws += (size_t)2 * NCHUNK * D_INNER * 4;     // 0.8 MB
    float* carryb  = (float*)ws;                                             // 12.6 MB

    const int nWin  = D_XZ * D_MODEL;
    const int nWout = D_MODEL * D_INNER;
    cvt_bf16_k<<<(nWin / 4 + 255) / 256, 256, 0, stream>>>(W_in,  Win_bf,  nWin / 4);
    cvt_bf16_k<<<(nWout / 4 + 255) / 256, 256, 0, stream>>>(W_out, Wout_bf, nWout / 4);
    cvt_pad_k<<<(XDS * D_INNER + 255) / 256, 256, 0, stream>>>(
        W_xp, Wxp_bf, 80 * D_INNER, XDS * D_INNER);
    cvt_pad2d_k<<<(D_INNER * 64 + 255) / 256, 256, 0, stream>>>(W_dt, Wdt_bf, D_INNER);

    layernorm_k<<<NROW, 256, 0, stream>>>(x, ln_g, ln_b, h_bf);
    // GEMM1: 2048x3072x768, 128x128 tiles -> 384 blocks
    gemm128<4, 4, true, false><<<dim3(NROW / 128, D_XZ / 128), 256, 0, stream>>>(
        h_bf, Win_bf, nullptr, xz_bf, NROW, D_XZ, D_MODEL);
    conv_silu_k<<<NROW * D_INNER / 256, 256, 0, stream>>>(xz_bf, conv_w, conv_b, xc_bf);
    // xproj: 2048x128x1536 (f32 out) + dt_r bf16 extraction
    gemm_bt64<0><<<dim3(NROW / 64, XDS / 64), 256, 0, stream>>>(
        xc_bf, Wxp_bf, nullptr, xdbl, NROW, XDS, D_INNER, XDS, dtr_bf);
    // dt: 2048x1536x64 with bias+softplus epilogue
    gemm_bt64<1><<<dim3(NROW / 64, D_INNER / 64), 256, 0, stream>>>(
        dtr_bf, Wdt_bf, b_dt, dtbuf, NROW, D_INNER, 64, D_INNER, nullptr);

    scan_p1<<<2 * NCHUNK * D_INNER / 256, 256, 0, stream>>>(
        dtbuf, xc_bf, xdbl, A_log, Sbuf, dtsumb);
    scan_p2<<<2 * D_INNER * D_STATE / 256, 256, 0, stream>>>(
        Sbuf, dtsumb, A_log, carryb);
    scan_p3<<<2 * NCHUNK * D_INNER / 256, 256, 0, stream>>>(
        dtbuf, xc_bf, xz_bf, xdbl, A_log, Dp, carryb, yybuf);

    // GEMM-out: 2048x768x1536, 64x128 tiles -> 192 blocks, fused +x residual
    gemm128<2, 4, false, true><<<dim3(NROW / 64, D_MODEL / 128), 256, 0, stream>>>(
        yybuf, Wout_bf, x, out, NROW, D_MODEL, D_INNER);
}

// Round 5
// 244.636 us; speedup vs baseline: 3.6916x; 1.0001x over previous
//
#include <hip/hip_runtime.h>

typedef unsigned short u16;
typedef unsigned int u32;
typedef __attribute__((ext_vector_type(8))) short short8;
typedef __attribute__((ext_vector_type(4))) float f32x4;

#define D_MODEL 768
#define D_INNER 1536
#define D_XZ    3072
#define D_STATE 16
#define DT_RANK 48
#define NROW    2048   // B*T
#define SEQ     1024
#define XDS     128    // padded x_dbl row stride (48 dt_r | 16 B | 16 C | pad)
#define NCHUNK  32
#define CLEN    32     // SEQ / NCHUNK

typedef const __attribute__((address_space(1))) u32 glb_u32;
typedef __attribute__((address_space(3))) u32 lds_u32;

__device__ __forceinline__ float bf2f(u16 u) {
    union { unsigned int i; float f; } v; v.i = ((unsigned int)u) << 16; return v.f;
}
__device__ __forceinline__ u16 f2bf(float f) {
    union { float f; unsigned int i; } v; v.f = f;
    unsigned int r = v.i + 0x7fffu + ((v.i >> 16) & 1u);
    return (u16)(r >> 16);
}
__device__ __forceinline__ void g2lds16(const u16* g, u16* l) {
    __builtin_amdgcn_global_load_lds((glb_u32*)g, (lds_u32*)l, 16, 0, 0);
}

// ---------------- unified weight prep: Win, Wout, Wxp(pad128), Wdt(pad64) --
#define N0 (D_XZ * D_MODEL / 4)        // 589824
#define N1 (D_MODEL * D_INNER / 4)     // 294912
#define N2 (XDS * D_INNER / 4)         // 49152
#define N3 (D_INNER * 64 / 4)          // 24576
__global__ __launch_bounds__(256) void prep_weights_k(
    const float* __restrict__ W_in, const float* __restrict__ W_out,
    const float* __restrict__ W_xp, const float* __restrict__ W_dt,
    u16* __restrict__ Win_bf, u16* __restrict__ Wout_bf,
    u16* __restrict__ Wxp_bf, u16* __restrict__ Wdt_bf)
{
    int gid = blockIdx.x * 256 + threadIdx.x;
    if (gid < N0) {
        float4 v = *(const float4*)(W_in + (size_t)gid * 4);
        u16* o = Win_bf + (size_t)gid * 4;
        o[0]=f2bf(v.x); o[1]=f2bf(v.y); o[2]=f2bf(v.z); o[3]=f2bf(v.w);
    } else if (gid < N0 + N1) {
        int i = gid - N0;
        float4 v = *(const float4*)(W_out + (size_t)i * 4);
        u16* o = Wout_bf + (size_t)i * 4;
        o[0]=f2bf(v.x); o[1]=f2bf(v.y); o[2]=f2bf(v.z); o[3]=f2bf(v.w);
    } else if (gid < N0 + N1 + N2) {
        int i = gid - N0 - N1;
        int n = (i * 4) / D_INNER, k = (i * 4) % D_INNER;
        u16* o = Wxp_bf + (size_t)i * 4;
        if (n < 80) {
            float4 v = *(const float4*)(W_xp + (size_t)n * D_INNER + k);
            o[0]=f2bf(v.x); o[1]=f2bf(v.y); o[2]=f2bf(v.z); o[3]=f2bf(v.w);
        } else { o[0]=0; o[1]=0; o[2]=0; o[3]=0; }
    } else if (gid < N0 + N1 + N2 + N3) {
        int i = gid - N0 - N1 - N2;
        int r = (i * 4) >> 6, c0 = (i * 4) & 63;
        u16* o = Wdt_bf + (size_t)i * 4;
        if (c0 < DT_RANK) {
            float4 v = *(const float4*)(W_dt + (size_t)r * DT_RANK + c0);
            o[0]=f2bf(v.x); o[1]=f2bf(v.y); o[2]=f2bf(v.z); o[3]=f2bf(v.w);
        } else { o[0]=0; o[1]=0; o[2]=0; o[3]=0; }
    }
}

// ---------------- LayerNorm: one block per row; f32 in, bf16 out -----------
__global__ __launch_bounds__(256) void layernorm_k(
    const float* __restrict__ x, const float* __restrict__ g,
    const float* __restrict__ b, u16* __restrict__ h)
{
    int row = blockIdx.x, tid = threadIdx.x;
    const float* xr = x + (size_t)row * D_MODEL;
    float v[3], s = 0.f, sq = 0.f;
#pragma unroll
    for (int j = 0; j < 3; ++j) {
        v[j] = xr[tid + j * 256];
        s += v[j]; sq += v[j] * v[j];
    }
#pragma unroll
    for (int off = 32; off >= 1; off >>= 1) {
        s  += __shfl_xor(s,  off, 64);
        sq += __shfl_xor(sq, off, 64);
    }
    __shared__ float sred[4], sqred[4];
    if ((tid & 63) == 0) { sred[tid >> 6] = s; sqred[tid >> 6] = sq; }
    __syncthreads();
    float st = sred[0] + sred[1] + sred[2] + sred[3];
    float sqt = sqred[0] + sqred[1] + sqred[2] + sqred[3];
    float mu = st * (1.f / D_MODEL);
    float var = sqt * (1.f / D_MODEL) - mu * mu;
    float rstd = rsqrtf(var + 1e-5f);
    u16* hr = h + (size_t)row * D_MODEL;
#pragma unroll
    for (int j = 0; j < 3; ++j) {
        int idx = tid + j * 256;
        hr[idx] = f2bf((v[j] - mu) * rstd * g[idx] + b[idx]);
    }
}

// ============ m97-style MFMA GEMM: C(MxN) = A(MxK) * B(NxK)^T ==============
// 4 waves in 2x2; wave tile (MT*16)x(NT*16); BM=32*MT, BN=32*NT.
// global_load_lds width-16 staging, XOR colblock swizzle (2-way max = free).
template<int MT, int NT, bool OUT_BF16, bool ADD_RES>
__global__ __launch_bounds__(256) void gemm128(
    const u16* __restrict__ A, const u16* __restrict__ B,
    const float* __restrict__ Res, void* __restrict__ Cv,
    int M, int N, int K)
{
    constexpr int BM = 32 * MT, BN = 32 * NT;
    __shared__ __align__(16) u16 As[BM * 32];
    __shared__ __align__(16) u16 Bs[BN * 32];
    int tid = threadIdx.x, w = tid >> 6, lane = tid & 63;
    int wm = w & 1, wn = w >> 1;
    int m0 = blockIdx.x * BM, n0 = blockIdx.y * BN;
    int mloc = lane & 15, quad = lane >> 4;
    int lr = lane >> 2, lc = lane & 3;
    f32x4 acc[MT][NT] = {};

    for (int k0 = 0; k0 < K; k0 += 32) {
        __syncthreads();
#pragma unroll
        for (int j = w; j < 2 * MT; j += 4) {
            int row = j * 16 + lr;
            int cb = lc ^ ((row >> 1) & 3);
            g2lds16(A + (size_t)(m0 + row) * K + k0 + cb * 8, &As[j * 512]);
        }
#pragma unroll
        for (int j = w; j < 2 * NT; j += 4) {
            int row = j * 16 + lr;
            int cb = lc ^ ((row >> 1) & 3);
            g2lds16(B + (size_t)(n0 + row) * K + k0 + cb * 8, &Bs[j * 512]);
        }
        __syncthreads();
        short8 afr[MT], bfr[NT];
#pragma unroll
        for (int mt = 0; mt < MT; ++mt) {
            int row = wm * MT * 16 + mt * 16 + mloc;
            int cb = quad ^ ((row >> 1) & 3);
            afr[mt] = *(const short8*)(&As[row * 32 + cb * 8]);
        }
#pragma unroll
        for (int nt = 0; nt < NT; ++nt) {
            int row = wn * NT * 16 + nt * 16 + mloc;
            int cb = quad ^ ((row >> 1) & 3);
            bfr[nt] = *(const short8*)(&Bs[row * 32 + cb * 8]);
        }
#pragma unroll
        for (int mt = 0; mt < MT; ++mt)
#pragma unroll
            for (int nt = 0; nt < NT; ++nt)
                acc[mt][nt] = __builtin_amdgcn_mfma_f32_16x16x32_bf16(
                    afr[mt], bfr[nt], acc[mt][nt], 0, 0, 0);
    }
    // C/D layout: col = lane&15, row = quad*4 + reg  [verified m89/m91]
#pragma unroll
    for (int mt = 0; mt < MT; ++mt) {
        int grow0 = m0 + wm * MT * 16 + mt * 16 + quad * 4;
#pragma unroll
        for (int nt = 0; nt < NT; ++nt) {
            int gcol = n0 + wn * NT * 16 + nt * 16 + mloc;
#pragma unroll
            for (int r = 0; r < 4; ++r) {
                size_t idx = (size_t)(grow0 + r) * N + gcol;
                float v = acc[mt][nt][r];
                if (ADD_RES) v += Res[idx];
                if (OUT_BF16) ((u16*)Cv)[idx] = f2bf(v);
                else          ((float*)Cv)[idx] = v;
            }
        }
    }
}

// ---------------- xproj split-K: xdbl(2048x128) += xc(.,Kslice)@Wxp^T ------
// 64x128 tile, grid (M/64, 8); K-slice 192 = 6 iters; f32 atomic epilogue.
__global__ __launch_bounds__(256) void xproj_splitk(
    const u16* __restrict__ A, const u16* __restrict__ B, float* __restrict__ Cout)
{
    constexpr int MT = 2, NT = 4;
    __shared__ __align__(16) u16 As[64 * 32];
    __shared__ __align__(16) u16 Bs[128 * 32];
    int tid = threadIdx.x, w = tid >> 6, lane = tid & 63;
    int wm = w & 1, wn = w >> 1;
    int m0 = blockIdx.x * 64;
    int kbase = blockIdx.y * 192;
    int mloc = lane & 15, quad = lane >> 4;
    int lr = lane >> 2, lc = lane & 3;
    f32x4 acc[MT][NT] = {};

    for (int k0 = 0; k0 < 192; k0 += 32) {
        __syncthreads();
#pragma unroll
        for (int j = w; j < 2 * MT; j += 4) {
            int row = j * 16 + lr;
            int cb = lc ^ ((row >> 1) & 3);
            g2lds16(A + (size_t)(m0 + row) * D_INNER + kbase + k0 + cb * 8, &As[j * 512]);
        }
#pragma unroll
        for (int j = w; j < 2 * NT; j += 4) {
            int row = j * 16 + lr;
            int cb = lc ^ ((row >> 1) & 3);
            g2lds16(B + (size_t)row * D_INNER + kbase + k0 + cb * 8, &Bs[j * 512]);
        }
        __syncthreads();
        short8 afr[MT], bfr[NT];
#pragma unroll
        for (int mt = 0; mt < MT; ++mt) {
            int row = wm * MT * 16 + mt * 16 + mloc;
            int cb = quad ^ ((row >> 1) & 3);
            afr[mt] = *(const short8*)(&As[row * 32 + cb * 8]);
        }
#pragma unroll
        for (int nt = 0; nt < NT; ++nt) {
            int row = wn * NT * 16 + nt * 16 + mloc;
            int cb = quad ^ ((row >> 1) & 3);
            bfr[nt] = *(const short8*)(&Bs[row * 32 + cb * 8]);
        }
#pragma unroll
        for (int mt = 0; mt < MT; ++mt)
#pragma unroll
            for (int nt = 0; nt < NT; ++nt)
                acc[mt][nt] = __builtin_amdgcn_mfma_f32_16x16x32_bf16(
                    afr[mt], bfr[nt], acc[mt][nt], 0, 0, 0);
    }
#pragma unroll
    for (int mt = 0; mt < MT; ++mt) {
        int grow0 = m0 + wm * MT * 16 + mt * 16 + quad * 4;
#pragma unroll
        for (int nt = 0; nt < NT; ++nt) {
            int gcol = wn * NT * 16 + nt * 16 + mloc;
#pragma unroll
            for (int r = 0; r < 4; ++r)
                unsafeAtomicAdd(&Cout[(size_t)(grow0 + r) * XDS + gcol], acc[mt][nt][r]);
        }
    }
}

// ---------------- dt GEMM: dt = softplus(xdbl[:, :64] @ Wdt_pad^T + b) -----
// M=2048, N=1536, K=64. A direct from global f32 (cols 48..63 x zero-weights),
// B staged once in LDS. Output bf16.
__global__ __launch_bounds__(256) void dtgemm_k(
    const float* __restrict__ xdbl, const u16* __restrict__ Wdt,
    const float* __restrict__ bias, u16* __restrict__ dtout)
{
    __shared__ __align__(16) u16 Bs[64 * 72];
    int tid = threadIdx.x, wave = tid >> 6, lane = tid & 63;
    int m0 = blockIdx.x * 64, n0 = blockIdx.y * 64;
    int mloc = lane & 15, quad = lane >> 4;
    {
        int r = tid >> 3, ck = (tid & 7) * 8;
#pragma unroll
        for (int rr = 0; rr < 64; rr += 32) {
            int4 bv = *(const int4*)(Wdt + (size_t)(n0 + r + rr) * 64 + ck);
            *(int4*)(&Bs[(r + rr) * 72 + ck]) = bv;
        }
    }
    int arow = m0 + wave * 16 + mloc;
    const float* ar = xdbl + (size_t)arow * XDS + quad * 8;
    short8 af[2];
#pragma unroll
    for (int h = 0; h < 2; ++h) {
        float4 a0 = *(const float4*)(ar + h * 32);
        float4 a1 = *(const float4*)(ar + h * 32 + 4);
        short8 t;
        t[0]=(short)f2bf(a0.x); t[1]=(short)f2bf(a0.y);
        t[2]=(short)f2bf(a0.z); t[3]=(short)f2bf(a0.w);
        t[4]=(short)f2bf(a1.x); t[5]=(short)f2bf(a1.y);
        t[6]=(short)f2bf(a1.z); t[7]=(short)f2bf(a1.w);
        af[h] = t;
    }
    __syncthreads();
    f32x4 acc[4] = {};
#pragma unroll
    for (int h = 0; h < 2; ++h)
#pragma unroll
        for (int nt = 0; nt < 4; ++nt) {
            short8 bf = *(const short8*)(&Bs[(nt * 16 + mloc) * 72 + h * 32 + quad * 8]);
            acc[nt] = __builtin_amdgcn_mfma_f32_16x16x32_bf16(af[h], bf, acc[nt], 0, 0, 0);
        }
#pragma unroll
    for (int nt = 0; nt < 4; ++nt) {
        int gcol = n0 + nt * 16 + mloc;
        int grow = m0 + wave * 16 + quad * 4;
#pragma unroll
        for (int r = 0; r < 4; ++r) {
            float t = acc[nt][r] + bias[gcol];
            float sp = (t > 15.f) ? t : __logf(1.f + __expf(t));
            dtout[(size_t)(grow + r) * D_INNER + gcol] = f2bf(sp);
        }
    }
}

// ---------------- depthwise causal conv4 + SiLU (4-wide in c) --------------
__global__ __launch_bounds__(256) void conv_silu_k(
    const u16* __restrict__ xz, const float* __restrict__ cw,
    const float* __restrict__ cb, u16* __restrict__ xc)
{
    int gid = blockIdx.x * 256 + threadIdx.x;     // NROW * D_INNER/4
    int r = gid / (D_INNER / 4);
    int c4 = (gid - r * (D_INNER / 4)) * 4;
    int t = r & (SEQ - 1);
    float4 cbv = *(const float4*)(cb + c4);
    float acc[4] = {cbv.x, cbv.y, cbv.z, cbv.w};
    float4 wv[4];
#pragma unroll
    for (int j = 0; j < 4; ++j) wv[j] = *(const float4*)(cw + (c4 + j) * 4);
#pragma unroll
    for (int k = 0; k < 4; ++k) {
        int tt = t - 3 + k;
        if (tt >= 0) {
            ushort4 xv = *(const ushort4*)(xz + (size_t)(r - 3 + k) * D_XZ + c4);
            acc[0] += bf2f(xv.x) * ((const float*)&wv[0])[k];
            acc[1] += bf2f(xv.y) * ((const float*)&wv[1])[k];
            acc[2] += bf2f(xv.z) * ((const float*)&wv[2])[k];
            acc[3] += bf2f(xv.w) * ((const float*)&wv[3])[k];
        }
    }
    ushort4 o;
    o.x = f2bf(acc[0] / (1.f + __expf(-acc[0])));
    o.y = f2bf(acc[1] / (1.f + __expf(-acc[1])));
    o.z = f2bf(acc[2] / (1.f + __expf(-acc[2])));
    o.w = f2bf(acc[3] / (1.f + __expf(-acc[3])));
    *(ushort4*)(xc + (size_t)r * D_INNER + c4) = o;
}

// ================= chunked parallel scan ===================================
__global__ __launch_bounds__(256) void scan_p1(
    const u16* __restrict__ dt, const u16* __restrict__ xc,
    const float* __restrict__ xdbl, const float* __restrict__ A_log,
    float* __restrict__ Sbuf, float* __restrict__ dtsumbuf)
{
    int gid = blockIdx.x * 256 + threadIdx.x;   // B*NCHUNK*D_INNER
    int d = gid % D_INNER;
    int bcN = gid / D_INNER;
    int c = bcN % NCHUNK;
    int b = bcN / NCHUNK;
    float a[D_STATE], s[D_STATE];
#pragma unroll
    for (int n = 0; n < D_STATE; ++n) {
        a[n] = -__expf(A_log[d * D_STATE + n]);
        s[n] = 0.f;
    }
    float dtsum = 0.f;
    size_t r0 = (size_t)b * SEQ + c * CLEN;
    for (int t = 0; t < CLEN; ++t) {
        size_t r = r0 + t;
        float dtv = bf2f(dt[r * D_INNER + d]);
        float du = dtv * bf2f(xc[r * D_INNER + d]);
        dtsum += dtv;
        const float* row = xdbl + r * XDS + DT_RANK;
        float4 B0 = *(const float4*)(row);
        float4 B1 = *(const float4*)(row + 4);
        float4 B2 = *(const float4*)(row + 8);
        float4 B3 = *(const float4*)(row + 12);
        float Bv[16] = {B0.x,B0.y,B0.z,B0.w,B1.x,B1.y,B1.z,B1.w,
                        B2.x,B2.y,B2.z,B2.w,B3.x,B3.y,B3.z,B3.w};
#pragma unroll
        for (int n = 0; n < D_STATE; ++n)
            s[n] = __expf(dtv * a[n]) * s[n] + du * Bv[n];
    }
    float4* So = (float4*)(Sbuf + (size_t)gid * D_STATE);
#pragma unroll
    for (int j = 0; j < 4; ++j)
        So[j] = make_float4(s[j*4], s[j*4+1], s[j*4+2], s[j*4+3]);
    dtsumbuf[gid] = dtsum;
}

__global__ __launch_bounds__(256) void scan_p2(
    const float* __restrict__ Sbuf, const float* __restrict__ dtsumbuf,
    const float* __restrict__ A_log, float* __restrict__ carry)
{
    int gid = blockIdx.x * 256 + threadIdx.x;   // B*D_INNER*16
    int n = gid % D_STATE;
    int d = (gid / D_STATE) % D_INNER;
    int b = gid / (D_STATE * D_INNER);
    float a = -__expf(A_log[d * D_STATE + n]);
    float s = 0.f;
    for (int c = 0; c < NCHUNK; ++c) {
        size_t idx = ((size_t)(b * NCHUNK + c) * D_INNER + d);
        carry[idx * D_STATE + n] = s;
        s = Sbuf[idx * D_STATE + n] + __expf(a * dtsumbuf[idx]) * s;
    }
}

__global__ __launch_bounds__(256) void scan_p3(
    const u16* __restrict__ dt, const u16* __restrict__ xc,
    const u16* __restrict__ xz, const float* __restrict__ xdbl,
    const float* __restrict__ A_log, const float* __restrict__ Dp,
    const float* __restrict__ carry, u16* __restrict__ yy)
{
    int gid = blockIdx.x * 256 + threadIdx.x;   // B*NCHUNK*D_INNER
    int d = gid % D_INNER;
    int bcN = gid / D_INNER;
    int c = bcN % NCHUNK;
    int b = bcN / NCHUNK;
    float a[D_STATE], s[D_STATE];
    const float4* Ci = (const float4*)(carry + (size_t)gid * D_STATE);
    float4 c0 = Ci[0], c1 = Ci[1], c2 = Ci[2], c3 = Ci[3];
    s[0]=c0.x; s[1]=c0.y; s[2]=c0.z; s[3]=c0.w;
    s[4]=c1.x; s[5]=c1.y; s[6]=c1.z; s[7]=c1.w;
    s[8]=c2.x; s[9]=c2.y; s[10]=c2.z; s[11]=c2.w;
    s[12]=c3.x; s[13]=c3.y; s[14]=c3.z; s[15]=c3.w;
#pragma unroll
    for (int n = 0; n < D_STATE; ++n)
        a[n] = -__expf(A_log[d * D_STATE + n]);
    float dpv = Dp[d];
    size_t r0 = (size_t)b * SEQ + c * CLEN;
    for (int t = 0; t < CLEN; ++t) {
        size_t r = r0 + t;
        float dtv = bf2f(dt[r * D_INNER + d]);
        float xcv = bf2f(xc[r * D_INNER + d]);
        float zv  = bf2f(xz[r * D_XZ + D_INNER + d]);
        float du = dtv * xcv;
        const float* row = xdbl + r * XDS + DT_RANK;
        float4 B0 = *(const float4*)(row);
        float4 B1 = *(const float4*)(row + 4);
        float4 B2 = *(const float4*)(row + 8);
        float4 B3 = *(const float4*)(row + 12);
        float4 C0 = *(const float4*)(row + 16);
        float4 C1 = *(const float4*)(row + 20);
        float4 C2 = *(const float4*)(row + 24);
        float4 C3 = *(const float4*)(row + 28);
        float Bv[16] = {B0.x,B0.y,B0.z,B0.w,B1.x,B1.y,B1.z,B1.w,
                        B2.x,B2.y,B2.z,B2.w,B3.x,B3.y,B3.z,B3.w};
        float Cv[16] = {C0.x,C0.y,C0.z,C0.w,C1.x,C1.y,C1.z,C1.w,
                        C2.x,C2.y,C2.z,C2.w,C3.x,C3.y,C3.z,C3.w};
        float y = 0.f;
#pragma unroll
        for (int n = 0; n < D_STATE; ++n) {
            s[n] = __expf(dtv * a[n]) * s[n] + du * Bv[n];
            y += s[n] * Cv[n];
        }
        float yv = y + dpv * xcv;
        float sig = 1.f / (1.f + __expf(-zv));
        yy[r * D_INNER + d] = f2bf(yv * (zv * sig));
    }
}

extern "C" void kernel_launch(void* const* d_in, const int* in_sizes, int n_in,
                              void* d_out, int out_size, void* d_ws, size_t ws_size,
                              hipStream_t stream) {
    const float* x      = (const float*)d_in[0];
    const float* ln_g   = (const float*)d_in[1];
    const float* ln_b   = (const float*)d_in[2];
    const float* W_in   = (const float*)d_in[3];
    const float* conv_w = (const float*)d_in[4];
    const float* conv_b = (const float*)d_in[5];
    const float* W_xp   = (const float*)d_in[6];
    const float* W_dt   = (const float*)d_in[7];
    const float* b_dt   = (const float*)d_in[8];
    const float* A_log  = (const float*)d_in[9];
    const float* Dp     = (const float*)d_in[10];
    const float* W_out  = (const float*)d_in[11];
    float* out = (float*)d_out;

    char* ws = (char*)d_ws;
    u16*   h_bf    = (u16*)ws;   ws += (size_t)NROW * D_MODEL * 2;
    u16*   xz_bf   = (u16*)ws;   ws += (size_t)NROW * D_XZ * 2;
    u16*   xc_bf   = (u16*)ws;   ws += (size_t)NROW * D_INNER * 2;
    float* xdbl    = (float*)ws; ws += (size_t)NROW * XDS * 4;
    u16*   dtbuf   = (u16*)ws;   ws += (size_t)NROW * D_INNER * 2;
    u16*   yybuf   = (u16*)ws;   ws += (size_t)NROW * D_INNER * 2;
    u16*   Win_bf  = (u16*)ws;   ws += (size_t)D_XZ * D_MODEL * 2;
    u16*   Wout_bf = (u16*)ws;   ws += (size_t)D_MODEL * D_INNER * 2;
    u16*   Wxp_bf  = (u16*)ws;   ws += (size_t)XDS * D_INNER * 2;
    u16*   Wdt_bf  = (u16*)ws;   ws += (size_t)D_INNER * 64 * 2;
    float* Sbuf    = (float*)ws; ws += (size_t)2 * NCHUNK * D_INNER * 16 * 4;
    float* dtsumb  = (float*)ws; ws += (size_t)2 * NCHUNK * D_INNER * 4;
    float* carryb  = (float*)ws;

    prep_weights_k<<<(N0 + N1 + N2 + N3 + 255) / 256, 256, 0, stream>>>(
        W_in, W_out, W_xp, W_dt, Win_bf, Wout_bf, Wxp_bf, Wdt_bf);
    hipMemsetAsync(xdbl, 0, (size_t)NROW * XDS * 4, stream);

    layernorm_k<<<NROW, 256, 0, stream>>>(x, ln_g, ln_b, h_bf);
    // GEMM1: 2048x3072x768, 128x128 tiles -> 384 blocks
    gemm128<4, 4, true, false><<<dim3(NROW / 128, D_XZ / 128), 256, 0, stream>>>(
        h_bf, Win_bf, nullptr, xz_bf, NROW, D_XZ, D_MODEL);
    conv_silu_k<<<NROW * (D_INNER / 4) / 256, 256, 0, stream>>>(
        xz_bf, conv_w, conv_b, xc_bf);
    // xproj: split-K x8, 256 blocks, atomic f32 accumulate into xdbl
    xproj_splitk<<<dim3(NROW / 64, 8), 256, 0, stream>>>(xc_bf, Wxp_bf, xdbl);
    // dt: 2048x1536x64, A direct-from-global, bf16 out; 768 blocks
    dtgemm_k<<<dim3(NROW / 64, D_INNER / 64), 256, 0, stream>>>(
        xdbl, Wdt_bf, b_dt, dtbuf);

    scan_p1<<<2 * NCHUNK * D_INNER / 256, 256, 0, stream>>>(
        dtbuf, xc_bf, xdbl, A_log, Sbuf, dtsumb);
    scan_p2<<<2 * D_INNER * D_STATE / 256, 256, 0, stream>>>(
        Sbuf, dtsumb, A_log, carryb);
    scan_p3<<<2 * NCHUNK * D_INNER / 256, 256, 0, stream>>>(
        dtbuf, xc_bf, xz_bf, xdbl, A_log, Dp, carryb, yybuf);

    // GEMM-out: 2048x768x1536, 64x64 tiles -> 384 blocks, fused +x residual
    gemm128<2, 2, false, true><<<dim3(NROW / 64, D_MODEL / 64), 256, 0, stream>>>(
        yybuf, Wout_bf, x, out, NROW, D_MODEL, D_INNER);
}

// Round 6
// 211.828 us; speedup vs baseline: 4.2633x; 1.1549x over previous
//
#include <hip/hip_runtime.h>

typedef unsigned short u16;
typedef unsigned int u32;
typedef __attribute__((ext_vector_type(8))) short short8;
typedef __attribute__((ext_vector_type(4))) float f32x4;

#define D_MODEL 768
#define D_INNER 1536
#define D_XZ    3072
#define D_STATE 16
#define DT_RANK 48
#define NROW    2048   // B*T
#define SEQ     1024
#define XDS     128    // padded x_dbl row stride (48 dt_r | 16 B | 16 C | pad)
#define NCHUNK  128
#define CLEN    8      // SEQ / NCHUNK

typedef const __attribute__((address_space(1))) u32 glb_u32;
typedef __attribute__((address_space(3))) u32 lds_u32;

__device__ __forceinline__ float bf2f(u16 u) {
    union { unsigned int i; float f; } v; v.i = ((unsigned int)u) << 16; return v.f;
}
__device__ __forceinline__ u16 f2bf(float f) {
    union { float f; unsigned int i; } v; v.f = f;
    unsigned int r = v.i + 0x7fffu + ((v.i >> 16) & 1u);
    return (u16)(r >> 16);
}
__device__ __forceinline__ void g2lds16(const u16* g, u16* l) {
    __builtin_amdgcn_global_load_lds((glb_u32*)g, (lds_u32*)l, 16, 0, 0);
}

// ------- unified prep: Win, Wout, Wxp(pad128), Wdt(pad64), negA, zero xdbl -
#define N0 (D_XZ * D_MODEL / 4)        // 589824
#define N1 (D_MODEL * D_INNER / 4)     // 294912
#define N2 (XDS * D_INNER / 4)         // 49152
#define N3 (D_INNER * 64 / 4)          // 24576
#define N4 (D_INNER * D_STATE / 4)     // 6144
#define N5 (NROW * XDS / 4)            // 65536
__global__ __launch_bounds__(256) void prep_weights_k(
    const float* __restrict__ W_in, const float* __restrict__ W_out,
    const float* __restrict__ W_xp, const float* __restrict__ W_dt,
    const float* __restrict__ A_log,
    u16* __restrict__ Win_bf, u16* __restrict__ Wout_bf,
    u16* __restrict__ Wxp_bf, u16* __restrict__ Wdt_bf,
    float* __restrict__ negA, float* __restrict__ xdbl)
{
    int gid = blockIdx.x * 256 + threadIdx.x;
    if (gid < N0) {
        float4 v = *(const float4*)(W_in + (size_t)gid * 4);
        u16* o = Win_bf + (size_t)gid * 4;
        o[0]=f2bf(v.x); o[1]=f2bf(v.y); o[2]=f2bf(v.z); o[3]=f2bf(v.w);
    } else if (gid < N0 + N1) {
        int i = gid - N0;
        float4 v = *(const float4*)(W_out + (size_t)i * 4);
        u16* o = Wout_bf + (size_t)i * 4;
        o[0]=f2bf(v.x); o[1]=f2bf(v.y); o[2]=f2bf(v.z); o[3]=f2bf(v.w);
    } else if (gid < N0 + N1 + N2) {
        int i = gid - N0 - N1;
        int n = (i * 4) / D_INNER, k = (i * 4) % D_INNER;
        u16* o = Wxp_bf + (size_t)i * 4;
        if (n < 80) {
            float4 v = *(const float4*)(W_xp + (size_t)n * D_INNER + k);
            o[0]=f2bf(v.x); o[1]=f2bf(v.y); o[2]=f2bf(v.z); o[3]=f2bf(v.w);
        } else { o[0]=0; o[1]=0; o[2]=0; o[3]=0; }
    } else if (gid < N0 + N1 + N2 + N3) {
        int i = gid - N0 - N1 - N2;
        int r = (i * 4) >> 6, c0 = (i * 4) & 63;
        u16* o = Wdt_bf + (size_t)i * 4;
        if (c0 < DT_RANK) {
            float4 v = *(const float4*)(W_dt + (size_t)r * DT_RANK + c0);
            o[0]=f2bf(v.x); o[1]=f2bf(v.y); o[2]=f2bf(v.z); o[3]=f2bf(v.w);
        } else { o[0]=0; o[1]=0; o[2]=0; o[3]=0; }
    } else if (gid < N0 + N1 + N2 + N3 + N4) {
        int i = gid - N0 - N1 - N2 - N3;
        float4 v = *(const float4*)(A_log + (size_t)i * 4);
        float4 o = make_float4(-__expf(v.x), -__expf(v.y), -__expf(v.z), -__expf(v.w));
        *(float4*)(negA + (size_t)i * 4) = o;
    } else if (gid < N0 + N1 + N2 + N3 + N4 + N5) {
        int i = gid - N0 - N1 - N2 - N3 - N4;
        *(float4*)(xdbl + (size_t)i * 4) = make_float4(0.f, 0.f, 0.f, 0.f);
    }
}

// ---------------- LayerNorm: one block per row; f32 in, bf16 out -----------
__global__ __launch_bounds__(256) void layernorm_k(
    const float* __restrict__ x, const float* __restrict__ g,
    const float* __restrict__ b, u16* __restrict__ h)
{
    int row = blockIdx.x, tid = threadIdx.x;
    const float* xr = x + (size_t)row * D_MODEL;
    float v[3], s = 0.f, sq = 0.f;
#pragma unroll
    for (int j = 0; j < 3; ++j) {
        v[j] = xr[tid + j * 256];
        s += v[j]; sq += v[j] * v[j];
    }
#pragma unroll
    for (int off = 32; off >= 1; off >>= 1) {
        s  += __shfl_xor(s,  off, 64);
        sq += __shfl_xor(sq, off, 64);
    }
    __shared__ float sred[4], sqred[4];
    if ((tid & 63) == 0) { sred[tid >> 6] = s; sqred[tid >> 6] = sq; }
    __syncthreads();
    float st = sred[0] + sred[1] + sred[2] + sred[3];
    float sqt = sqred[0] + sqred[1] + sqred[2] + sqred[3];
    float mu = st * (1.f / D_MODEL);
    float var = sqt * (1.f / D_MODEL) - mu * mu;
    float rstd = rsqrtf(var + 1e-5f);
    u16* hr = h + (size_t)row * D_MODEL;
#pragma unroll
    for (int j = 0; j < 3; ++j) {
        int idx = tid + j * 256;
        hr[idx] = f2bf((v[j] - mu) * rstd * g[idx] + b[idx]);
    }
}

// ============ m97-style MFMA GEMM: C(MxN) = A(MxK) * B(NxK)^T ==============
template<int MT, int NT, bool OUT_BF16, bool ADD_RES>
__global__ __launch_bounds__(256) void gemm128(
    const u16* __restrict__ A, const u16* __restrict__ B,
    const float* __restrict__ Res, void* __restrict__ Cv,
    int M, int N, int K)
{
    constexpr int BM = 32 * MT, BN = 32 * NT;
    __shared__ __align__(16) u16 As[BM * 32];
    __shared__ __align__(16) u16 Bs[BN * 32];
    int tid = threadIdx.x, w = tid >> 6, lane = tid & 63;
    int wm = w & 1, wn = w >> 1;
    int m0 = blockIdx.x * BM, n0 = blockIdx.y * BN;
    int mloc = lane & 15, quad = lane >> 4;
    int lr = lane >> 2, lc = lane & 3;
    f32x4 acc[MT][NT] = {};

    for (int k0 = 0; k0 < K; k0 += 32) {
        __syncthreads();
#pragma unroll
        for (int j = w; j < 2 * MT; j += 4) {
            int row = j * 16 + lr;
            int cb = lc ^ ((row >> 1) & 3);
            g2lds16(A + (size_t)(m0 + row) * K + k0 + cb * 8, &As[j * 512]);
        }
#pragma unroll
        for (int j = w; j < 2 * NT; j += 4) {
            int row = j * 16 + lr;
            int cb = lc ^ ((row >> 1) & 3);
            g2lds16(B + (size_t)(n0 + row) * K + k0 + cb * 8, &Bs[j * 512]);
        }
        __syncthreads();
        short8 afr[MT], bfr[NT];
#pragma unroll
        for (int mt = 0; mt < MT; ++mt) {
            int row = wm * MT * 16 + mt * 16 + mloc;
            int cb = quad ^ ((row >> 1) & 3);
            afr[mt] = *(const short8*)(&As[row * 32 + cb * 8]);
        }
#pragma unroll
        for (int nt = 0; nt < NT; ++nt) {
            int row = wn * NT * 16 + nt * 16 + mloc;
            int cb = quad ^ ((row >> 1) & 3);
            bfr[nt] = *(const short8*)(&Bs[row * 32 + cb * 8]);
        }
#pragma unroll
        for (int mt = 0; mt < MT; ++mt)
#pragma unroll
            for (int nt = 0; nt < NT; ++nt)
                acc[mt][nt] = __builtin_amdgcn_mfma_f32_16x16x32_bf16(
                    afr[mt], bfr[nt], acc[mt][nt], 0, 0, 0);
    }
#pragma unroll
    for (int mt = 0; mt < MT; ++mt) {
        int grow0 = m0 + wm * MT * 16 + mt * 16 + quad * 4;
#pragma unroll
        for (int nt = 0; nt < NT; ++nt) {
            int gcol = n0 + wn * NT * 16 + nt * 16 + mloc;
#pragma unroll
            for (int r = 0; r < 4; ++r) {
                size_t idx = (size_t)(grow0 + r) * N + gcol;
                float v = acc[mt][nt][r];
                if (ADD_RES) v += Res[idx];
                if (OUT_BF16) ((u16*)Cv)[idx] = f2bf(v);
                else          ((float*)Cv)[idx] = v;
            }
        }
    }
}

// ---------------- xproj split-K: xdbl(2048x128) += xc(.,Kslice)@Wxp^T ------
__global__ __launch_bounds__(256) void xproj_splitk(
    const u16* __restrict__ A, const u16* __restrict__ B, float* __restrict__ Cout)
{
    constexpr int MT = 2, NT = 4;
    __shared__ __align__(16) u16 As[64 * 32];
    __shared__ __align__(16) u16 Bs[128 * 32];
    int tid = threadIdx.x, w = tid >> 6, lane = tid & 63;
    int wm = w & 1, wn = w >> 1;
    int m0 = blockIdx.x * 64;
    int kbase = blockIdx.y * 192;
    int mloc = lane & 15, quad = lane >> 4;
    int lr = lane >> 2, lc = lane & 3;
    f32x4 acc[MT][NT] = {};

    for (int k0 = 0; k0 < 192; k0 += 32) {
        __syncthreads();
#pragma unroll
        for (int j = w; j < 2 * MT; j += 4) {
            int row = j * 16 + lr;
            int cb = lc ^ ((row >> 1) & 3);
            g2lds16(A + (size_t)(m0 + row) * D_INNER + kbase + k0 + cb * 8, &As[j * 512]);
        }
#pragma unroll
        for (int j = w; j < 2 * NT; j += 4) {
            int row = j * 16 + lr;
            int cb = lc ^ ((row >> 1) & 3);
            g2lds16(B + (size_t)row * D_INNER + kbase + k0 + cb * 8, &Bs[j * 512]);
        }
        __syncthreads();
        short8 afr[MT], bfr[NT];
#pragma unroll
        for (int mt = 0; mt < MT; ++mt) {
            int row = wm * MT * 16 + mt * 16 + mloc;
            int cb = quad ^ ((row >> 1) & 3);
            afr[mt] = *(const short8*)(&As[row * 32 + cb * 8]);
        }
#pragma unroll
        for (int nt = 0; nt < NT; ++nt) {
            int row = wn * NT * 16 + nt * 16 + mloc;
            int cb = quad ^ ((row >> 1) & 3);
            bfr[nt] = *(const short8*)(&Bs[row * 32 + cb * 8]);
        }
#pragma unroll
        for (int mt = 0; mt < MT; ++mt)
#pragma unroll
            for (int nt = 0; nt < NT; ++nt)
                acc[mt][nt] = __builtin_amdgcn_mfma_f32_16x16x32_bf16(
                    afr[mt], bfr[nt], acc[mt][nt], 0, 0, 0);
    }
#pragma unroll
    for (int mt = 0; mt < MT; ++mt) {
        int grow0 = m0 + wm * MT * 16 + mt * 16 + quad * 4;
#pragma unroll
        for (int nt = 0; nt < NT; ++nt) {
            int gcol = wn * NT * 16 + nt * 16 + mloc;
#pragma unroll
            for (int r = 0; r < 4; ++r)
                unsafeAtomicAdd(&Cout[(size_t)(grow0 + r) * XDS + gcol], acc[mt][nt][r]);
        }
    }
}

// ---------------- dt GEMM: dt = softplus(xdbl[:, :64] @ Wdt_pad^T + b) -----
__global__ __launch_bounds__(256) void dtgemm_k(
    const float* __restrict__ xdbl, const u16* __restrict__ Wdt,
    const float* __restrict__ bias, u16* __restrict__ dtout)
{
    __shared__ __align__(16) u16 Bs[64 * 72];
    int tid = threadIdx.x, wave = tid >> 6, lane = tid & 63;
    int m0 = blockIdx.x * 64, n0 = blockIdx.y * 64;
    int mloc = lane & 15, quad = lane >> 4;
    {
        int r = tid >> 3, ck = (tid & 7) * 8;
#pragma unroll
        for (int rr = 0; rr < 64; rr += 32) {
            int4 bv = *(const int4*)(Wdt + (size_t)(n0 + r + rr) * 64 + ck);
            *(int4*)(&Bs[(r + rr) * 72 + ck]) = bv;
        }
    }
    int arow = m0 + wave * 16 + mloc;
    const float* ar = xdbl + (size_t)arow * XDS + quad * 8;
    short8 af[2];
#pragma unroll
    for (int h = 0; h < 2; ++h) {
        float4 a0 = *(const float4*)(ar + h * 32);
        float4 a1 = *(const float4*)(ar + h * 32 + 4);
        short8 t;
        t[0]=(short)f2bf(a0.x); t[1]=(short)f2bf(a0.y);
        t[2]=(short)f2bf(a0.z); t[3]=(short)f2bf(a0.w);
        t[4]=(short)f2bf(a1.x); t[5]=(short)f2bf(a1.y);
        t[6]=(short)f2bf(a1.z); t[7]=(short)f2bf(a1.w);
        af[h] = t;
    }
    __syncthreads();
    f32x4 acc[4] = {};
#pragma unroll
    for (int h = 0; h < 2; ++h)
#pragma unroll
        for (int nt = 0; nt < 4; ++nt) {
            short8 bf = *(const short8*)(&Bs[(nt * 16 + mloc) * 72 + h * 32 + quad * 8]);
            acc[nt] = __builtin_amdgcn_mfma_f32_16x16x32_bf16(af[h], bf, acc[nt], 0, 0, 0);
        }
#pragma unroll
    for (int nt = 0; nt < 4; ++nt) {
        int gcol = n0 + nt * 16 + mloc;
        int grow = m0 + wave * 16 + quad * 4;
#pragma unroll
        for (int r = 0; r < 4; ++r) {
            float t = acc[nt][r] + bias[gcol];
            float sp = (t > 15.f) ? t : __logf(1.f + __expf(t));
            dtout[(size_t)(grow + r) * D_INNER + gcol] = f2bf(sp);
        }
    }
}

// ---------------- depthwise causal conv4 + SiLU (4-wide in c) --------------
__global__ __launch_bounds__(256) void conv_silu_k(
    const u16* __restrict__ xz, const float* __restrict__ cw,
    const float* __restrict__ cb, u16* __restrict__ xc)
{
    int gid = blockIdx.x * 256 + threadIdx.x;     // NROW * D_INNER/4
    int r = gid / (D_INNER / 4);
    int c4 = (gid - r * (D_INNER / 4)) * 4;
    int t = r & (SEQ - 1);
    float4 cbv = *(const float4*)(cb + c4);
    float acc[4] = {cbv.x, cbv.y, cbv.z, cbv.w};
    float4 wv[4];
#pragma unroll
    for (int j = 0; j < 4; ++j) wv[j] = *(const float4*)(cw + (c4 + j) * 4);
#pragma unroll
    for (int k = 0; k < 4; ++k) {
        int tt = t - 3 + k;
        if (tt >= 0) {
            ushort4 xv = *(const ushort4*)(xz + (size_t)(r - 3 + k) * D_XZ + c4);
            acc[0] += bf2f(xv.x) * ((const float*)&wv[0])[k];
            acc[1] += bf2f(xv.y) * ((const float*)&wv[1])[k];
            acc[2] += bf2f(xv.z) * ((const float*)&wv[2])[k];
            acc[3] += bf2f(xv.w) * ((const float*)&wv[3])[k];
        }
    }
    ushort4 o;
    o.x = f2bf(acc[0] / (1.f + __expf(-acc[0])));
    o.y = f2bf(acc[1] / (1.f + __expf(-acc[1])));
    o.z = f2bf(acc[2] / (1.f + __expf(-acc[2])));
    o.w = f2bf(acc[3] / (1.f + __expf(-acc[3])));
    *(ushort4*)(xc + (size_t)r * D_INNER + c4) = o;
}

// ================= chunked parallel scan (CLEN=8, LDS-staged B/C) ==========
// Block covers 256 consecutive d within one (b,c): D_INNER = 6*256.
__global__ __launch_bounds__(256) void scan_p1(
    const u16* __restrict__ dt, const u16* __restrict__ xc,
    const float* __restrict__ xdbl, const float* __restrict__ negA,
    float* __restrict__ Sbuf, float* __restrict__ dtsumbuf)
{
    __shared__ float Bsh[CLEN][D_STATE];
    int tid = threadIdx.x;
    int gid = blockIdx.x * 256 + tid;
    int d = gid % D_INNER;
    int bcN = gid / D_INNER;
    int c = bcN % NCHUNK, b = bcN / NCHUNK;
    size_t r0 = (size_t)b * SEQ + c * CLEN;
    if (tid < CLEN * D_STATE) {
        int tt = tid >> 4, n = tid & 15;
        Bsh[tt][n] = xdbl[(r0 + tt) * XDS + DT_RANK + n];
    }
    float a[D_STATE], s[D_STATE] = {};
    {
        const float4* Ar = (const float4*)(negA + d * D_STATE);
        float4 a0 = Ar[0], a1 = Ar[1], a2 = Ar[2], a3 = Ar[3];
        a[0]=a0.x; a[1]=a0.y; a[2]=a0.z; a[3]=a0.w;
        a[4]=a1.x; a[5]=a1.y; a[6]=a1.z; a[7]=a1.w;
        a[8]=a2.x; a[9]=a2.y; a[10]=a2.z; a[11]=a2.w;
        a[12]=a3.x; a[13]=a3.y; a[14]=a3.z; a[15]=a3.w;
    }
    float dtv[CLEN], du[CLEN];
    const u16* dp = dt + r0 * D_INNER + d;
    const u16* xp = xc + r0 * D_INNER + d;
#pragma unroll
    for (int t = 0; t < CLEN; ++t) {
        dtv[t] = bf2f(dp[t * D_INNER]);
        du[t] = dtv[t] * bf2f(xp[t * D_INNER]);
    }
    __syncthreads();
    float dtsum = 0.f;
#pragma unroll
    for (int t = 0; t < CLEN; ++t) {
        dtsum += dtv[t];
#pragma unroll
        for (int n = 0; n < D_STATE; ++n)
            s[n] = __expf(dtv[t] * a[n]) * s[n] + du[t] * Bsh[t][n];
    }
    float4* So = (float4*)(Sbuf + (size_t)gid * D_STATE);
#pragma unroll
    for (int j = 0; j < 4; ++j)
        So[j] = make_float4(s[j*4], s[j*4+1], s[j*4+2], s[j*4+3]);
    dtsumbuf[gid] = dtsum;
}

__global__ __launch_bounds__(256) void scan_p2(
    const float* __restrict__ Sbuf, const float* __restrict__ dtsumbuf,
    const float* __restrict__ negA, float* __restrict__ carry)
{
    int gid = blockIdx.x * 256 + threadIdx.x;   // B*D_INNER*16
    int n = gid % D_STATE;
    int d = (gid / D_STATE) % D_INNER;
    int b = gid / (D_STATE * D_INNER);
    float a = negA[d * D_STATE + n];
    float s = 0.f;
    for (int c = 0; c < NCHUNK; ++c) {
        size_t idx = ((size_t)(b * NCHUNK + c) * D_INNER + d);
        carry[idx * D_STATE + n] = s;
        s = Sbuf[idx * D_STATE + n] + __expf(a * dtsumbuf[idx]) * s;
    }
}

__global__ __launch_bounds__(256) void scan_p3(
    const u16* __restrict__ dt, const u16* __restrict__ xc,
    const u16* __restrict__ xz, const float* __restrict__ xdbl,
    const float* __restrict__ negA, const float* __restrict__ Dp,
    const float* __restrict__ carry, u16* __restrict__ yy)
{
    __shared__ float BCsh[CLEN][2 * D_STATE];
    int tid = threadIdx.x;
    int gid = blockIdx.x * 256 + tid;
    int d = gid % D_INNER;
    int bcN = gid / D_INNER;
    int c = bcN % NCHUNK, b = bcN / NCHUNK;
    size_t r0 = (size_t)b * SEQ + c * CLEN;
    {
        int tt = tid >> 5, j = tid & 31;   // 256 = 8 rows x 32 vals
        BCsh[tt][j] = xdbl[(r0 + tt) * XDS + DT_RANK + j];
    }
    float a[D_STATE], s[D_STATE];
    {
        const float4* Ci = (const float4*)(carry + (size_t)gid * D_STATE);
        float4 c0 = Ci[0], c1 = Ci[1], c2 = Ci[2], c3 = Ci[3];
        s[0]=c0.x; s[1]=c0.y; s[2]=c0.z; s[3]=c0.w;
        s[4]=c1.x; s[5]=c1.y; s[6]=c1.z; s[7]=c1.w;
        s[8]=c2.x; s[9]=c2.y; s[10]=c2.z; s[11]=c2.w;
        s[12]=c3.x; s[13]=c3.y; s[14]=c3.z; s[15]=c3.w;
        const float4* Ar = (const float4*)(negA + d * D_STATE);
        float4 a0 = Ar[0], a1 = Ar[1], a2 = Ar[2], a3 = Ar[3];
        a[0]=a0.x; a[1]=a0.y; a[2]=a0.z; a[3]=a0.w;
        a[4]=a1.x; a[5]=a1.y; a[6]=a1.z; a[7]=a1.w;
        a[8]=a2.x; a[9]=a2.y; a[10]=a2.z; a[11]=a2.w;
        a[12]=a3.x; a[13]=a3.y; a[14]=a3.z; a[15]=a3.w;
    }
    float dtv[CLEN], xcv[CLEN], zv[CLEN];
    const u16* dp = dt + r0 * D_INNER + d;
    const u16* xp = xc + r0 * D_INNER + d;
    const u16* zp = xz + r0 * D_XZ + D_INNER + d;
#pragma unroll
    for (int t = 0; t < CLEN; ++t) {
        dtv[t] = bf2f(dp[t * D_INNER]);
        xcv[t] = bf2f(xp[t * D_INNER]);
        zv[t]  = bf2f(zp[t * D_XZ]);
    }
    float dpv = Dp[d];
    __syncthreads();
    u16* yp = yy + r0 * D_INNER + d;
#pragma unroll
    for (int t = 0; t < CLEN; ++t) {
        float du = dtv[t] * xcv[t];
        float y = 0.f;
#pragma unroll
        for (int n = 0; n < D_STATE; ++n) {
            s[n] = __expf(dtv[t] * a[n]) * s[n] + du * BCsh[t][n];
            y += s[n] * BCsh[t][D_STATE + n];
        }
        float yv = y + dpv * xcv[t];
        float sig = 1.f / (1.f + __expf(-zv[t]));
        yp[t * D_INNER] = f2bf(yv * (zv[t] * sig));
    }
}

extern "C" void kernel_launch(void* const* d_in, const int* in_sizes, int n_in,
                              void* d_out, int out_size, void* d_ws, size_t ws_size,
                              hipStream_t stream) {
    const float* x      = (const float*)d_in[0];
    const float* ln_g   = (const float*)d_in[1];
    const float* ln_b   = (const float*)d_in[2];
    const float* W_in   = (const float*)d_in[3];
    const float* conv_w = (const float*)d_in[4];
    const float* conv_b = (const float*)d_in[5];
    const float* W_xp   = (const float*)d_in[6];
    const float* W_dt   = (const float*)d_in[7];
    const float* b_dt   = (const float*)d_in[8];
    const float* A_log  = (const float*)d_in[9];
    const float* Dp     = (const float*)d_in[10];
    const float* W_out  = (const float*)d_in[11];
    float* out = (float*)d_out;

    char* ws = (char*)d_ws;
    u16*   h_bf    = (u16*)ws;   ws += (size_t)NROW * D_MODEL * 2;
    u16*   xz_bf   = (u16*)ws;   ws += (size_t)NROW * D_XZ * 2;
    u16*   xc_bf   = (u16*)ws;   ws += (size_t)NROW * D_INNER * 2;
    float* xdbl    = (float*)ws; ws += (size_t)NROW * XDS * 4;
    u16*   dtbuf   = (u16*)ws;   ws += (size_t)NROW * D_INNER * 2;
    u16*   yybuf   = (u16*)ws;   ws += (size_t)NROW * D_INNER * 2;
    u16*   Win_bf  = (u16*)ws;   ws += (size_t)D_XZ * D_MODEL * 2;
    u16*   Wout_bf = (u16*)ws;   ws += (size_t)D_MODEL * D_INNER * 2;
    u16*   Wxp_bf  = (u16*)ws;   ws += (size_t)XDS * D_INNER * 2;
    u16*   Wdt_bf  = (u16*)ws;   ws += (size_t)D_INNER * 64 * 2;
    float* negA    = (float*)ws; ws += (size_t)D_INNER * D_STATE * 4;
    float* Sbuf    = (float*)ws; ws += (size_t)2 * NCHUNK * D_INNER * 16 * 4;
    float* dtsumb  = (float*)ws; ws += (size_t)2 * NCHUNK * D_INNER * 4;
    float* carryb  = (float*)ws;

    prep_weights_k<<<(N0 + N1 + N2 + N3 + N4 + N5 + 255) / 256, 256, 0, stream>>>(
        W_in, W_out, W_xp, W_dt, A_log, Win_bf, Wout_bf, Wxp_bf, Wdt_bf, negA, xdbl);

    layernorm_k<<<NROW, 256, 0, stream>>>(x, ln_g, ln_b, h_bf);
    gemm128<4, 4, true, false><<<dim3(NROW / 128, D_XZ / 128), 256, 0, stream>>>(
        h_bf, Win_bf, nullptr, xz_bf, NROW, D_XZ, D_MODEL);
    conv_silu_k<<<NROW * (D_INNER / 4) / 256, 256, 0, stream>>>(
        xz_bf, conv_w, conv_b, xc_bf);
    xproj_splitk<<<dim3(NROW / 64, 8), 256, 0, stream>>>(xc_bf, Wxp_bf, xdbl);
    dtgemm_k<<<dim3(NROW / 64, D_INNER / 64), 256, 0, stream>>>(
        xdbl, Wdt_bf, b_dt, dtbuf);

    scan_p1<<<2 * NCHUNK * D_INNER / 256, 256, 0, stream>>>(
        dtbuf, xc_bf, xdbl, negA, Sbuf, dtsumb);
    scan_p2<<<2 * D_INNER * D_STATE / 256, 256, 0, stream>>>(
        Sbuf, dtsumb, negA, carryb);
    scan_p3<<<2 * NCHUNK * D_INNER / 256, 256, 0, stream>>>(
        dtbuf, xc_bf, xz_bf, xdbl, negA, Dp, carryb, yybuf);

    gemm128<2, 2, false, true><<<dim3(NROW / 64, D_MODEL / 64), 256, 0, stream>>>(
        yybuf, Wout_bf, x, out, NROW, D_MODEL, D_INNER);
}

// Round 7
// 206.624 us; speedup vs baseline: 4.3707x; 1.0252x over previous
//
#include <hip/hip_runtime.h>

typedef unsigned short u16;
typedef unsigned int u32;
typedef __attribute__((ext_vector_type(8))) short short8;
typedef __attribute__((ext_vector_type(4))) float f32x4;

#define D_MODEL 768
#define D_INNER 1536
#define D_XZ    3072
#define D_STATE 16
#define DT_RANK 48
#define NROW    2048   // B*T
#define SEQ     1024
#define XDS     128    // padded x_dbl row stride (48 dt_r | 16 B | 16 C | pad)
#define NCHUNK  128
#define CLEN    8      // SEQ / NCHUNK

typedef const __attribute__((address_space(1))) u32 glb_u32;
typedef __attribute__((address_space(3))) u32 lds_u32;

__device__ __forceinline__ float bf2f(u16 u) {
    union { unsigned int i; float f; } v; v.i = ((unsigned int)u) << 16; return v.f;
}
__device__ __forceinline__ u16 f2bf(float f) {
    union { float f; unsigned int i; } v; v.f = f;
    unsigned int r = v.i + 0x7fffu + ((v.i >> 16) & 1u);
    return (u16)(r >> 16);
}
__device__ __forceinline__ void g2lds16(const u16* g, u16* l) {
    __builtin_amdgcn_global_load_lds((glb_u32*)g, (lds_u32*)l, 16, 0, 0);
}

// ======== fused prep: LayerNorm (blocks 0..2047) + weight prep/zeroing =====
#define N0 (D_XZ * D_MODEL / 4)        // 589824  Win->bf16
#define N1 (D_MODEL * D_INNER / 4)     // 294912  Wout->bf16
#define N2 (XDS * D_INNER / 4)         // 49152   Wxp pad128->bf16
#define N3 (D_INNER * 64 / 4)          // 24576   Wdt pad64->bf16
#define N4 (D_INNER * D_STATE / 4)     // 6144    negA
#define N5 (NROW * XDS / 4)            // 65536   zero xdbl
#define N6 (NROW * D_MODEL / 4)        // 393216  zero out
#define PREP_BLOCKS ((N0+N1+N2+N3+N4+N5+N6) / 256)   // 5560
__global__ __launch_bounds__(256) void prep_ln_k(
    const float* __restrict__ x, const float* __restrict__ g,
    const float* __restrict__ bln, u16* __restrict__ h,
    const float* __restrict__ W_in, const float* __restrict__ W_out,
    const float* __restrict__ W_xp, const float* __restrict__ W_dt,
    const float* __restrict__ A_log,
    u16* __restrict__ Win_bf, u16* __restrict__ Wout_bf,
    u16* __restrict__ Wxp_bf, u16* __restrict__ Wdt_bf,
    float* __restrict__ negA, float* __restrict__ xdbl,
    float* __restrict__ outz)
{
    __shared__ float sred[4], sqred[4];
    int tid = threadIdx.x;
    if (blockIdx.x < NROW) {
        int row = blockIdx.x;
        const float* xr = x + (size_t)row * D_MODEL;
        float v[3], s = 0.f, sq = 0.f;
#pragma unroll
        for (int j = 0; j < 3; ++j) {
            v[j] = xr[tid + j * 256];
            s += v[j]; sq += v[j] * v[j];
        }
#pragma unroll
        for (int off = 32; off >= 1; off >>= 1) {
            s  += __shfl_xor(s,  off, 64);
            sq += __shfl_xor(sq, off, 64);
        }
        if ((tid & 63) == 0) { sred[tid >> 6] = s; sqred[tid >> 6] = sq; }
        __syncthreads();
        float st = sred[0] + sred[1] + sred[2] + sred[3];
        float sqt = sqred[0] + sqred[1] + sqred[2] + sqred[3];
        float mu = st * (1.f / D_MODEL);
        float var = sqt * (1.f / D_MODEL) - mu * mu;
        float rstd = rsqrtf(var + 1e-5f);
        u16* hr = h + (size_t)row * D_MODEL;
#pragma unroll
        for (int j = 0; j < 3; ++j) {
            int idx = tid + j * 256;
            hr[idx] = f2bf((v[j] - mu) * rstd * g[idx] + bln[idx]);
        }
        return;
    }
    int gid = (blockIdx.x - NROW) * 256 + tid;
    if (gid < N0) {
        float4 v = *(const float4*)(W_in + (size_t)gid * 4);
        u16* o = Win_bf + (size_t)gid * 4;
        o[0]=f2bf(v.x); o[1]=f2bf(v.y); o[2]=f2bf(v.z); o[3]=f2bf(v.w);
    } else if (gid < N0 + N1) {
        int i = gid - N0;
        float4 v = *(const float4*)(W_out + (size_t)i * 4);
        u16* o = Wout_bf + (size_t)i * 4;
        o[0]=f2bf(v.x); o[1]=f2bf(v.y); o[2]=f2bf(v.z); o[3]=f2bf(v.w);
    } else if (gid < N0 + N1 + N2) {
        int i = gid - N0 - N1;
        int n = (i * 4) / D_INNER, k = (i * 4) % D_INNER;
        u16* o = Wxp_bf + (size_t)i * 4;
        if (n < 80) {
            float4 v = *(const float4*)(W_xp + (size_t)n * D_INNER + k);
            o[0]=f2bf(v.x); o[1]=f2bf(v.y); o[2]=f2bf(v.z); o[3]=f2bf(v.w);
        } else { o[0]=0; o[1]=0; o[2]=0; o[3]=0; }
    } else if (gid < N0 + N1 + N2 + N3) {
        int i = gid - N0 - N1 - N2;
        int r = (i * 4) >> 6, c0 = (i * 4) & 63;
        u16* o = Wdt_bf + (size_t)i * 4;
        if (c0 < DT_RANK) {
            float4 v = *(const float4*)(W_dt + (size_t)r * DT_RANK + c0);
            o[0]=f2bf(v.x); o[1]=f2bf(v.y); o[2]=f2bf(v.z); o[3]=f2bf(v.w);
        } else { o[0]=0; o[1]=0; o[2]=0; o[3]=0; }
    } else if (gid < N0 + N1 + N2 + N3 + N4) {
        int i = gid - N0 - N1 - N2 - N3;
        float4 v = *(const float4*)(A_log + (size_t)i * 4);
        *(float4*)(negA + (size_t)i * 4) =
            make_float4(-__expf(v.x), -__expf(v.y), -__expf(v.z), -__expf(v.w));
    } else if (gid < N0 + N1 + N2 + N3 + N4 + N5) {
        int i = gid - N0 - N1 - N2 - N3 - N4;
        *(float4*)(xdbl + (size_t)i * 4) = make_float4(0.f, 0.f, 0.f, 0.f);
    } else {
        int i = gid - N0 - N1 - N2 - N3 - N4 - N5;
        *(float4*)(outz + (size_t)i * 4) = make_float4(0.f, 0.f, 0.f, 0.f);
    }
}

// ============ m97-style MFMA GEMM: C(MxN) = A(MxK) * B(NxK)^T ==============
template<int MT, int NT, bool OUT_BF16>
__global__ __launch_bounds__(256) void gemm128(
    const u16* __restrict__ A, const u16* __restrict__ B,
    void* __restrict__ Cv, int M, int N, int K)
{
    constexpr int BM = 32 * MT, BN = 32 * NT;
    __shared__ __align__(16) u16 As[BM * 32];
    __shared__ __align__(16) u16 Bs[BN * 32];
    int tid = threadIdx.x, w = tid >> 6, lane = tid & 63;
    int wm = w & 1, wn = w >> 1;
    int m0 = blockIdx.x * BM, n0 = blockIdx.y * BN;
    int mloc = lane & 15, quad = lane >> 4;
    int lr = lane >> 2, lc = lane & 3;
    f32x4 acc[MT][NT] = {};

    for (int k0 = 0; k0 < K; k0 += 32) {
        __syncthreads();
#pragma unroll
        for (int j = w; j < 2 * MT; j += 4) {
            int row = j * 16 + lr;
            int cb = lc ^ ((row >> 1) & 3);
            g2lds16(A + (size_t)(m0 + row) * K + k0 + cb * 8, &As[j * 512]);
        }
#pragma unroll
        for (int j = w; j < 2 * NT; j += 4) {
            int row = j * 16 + lr;
            int cb = lc ^ ((row >> 1) & 3);
            g2lds16(B + (size_t)(n0 + row) * K + k0 + cb * 8, &Bs[j * 512]);
        }
        __syncthreads();
        short8 afr[MT], bfr[NT];
#pragma unroll
        for (int mt = 0; mt < MT; ++mt) {
            int row = wm * MT * 16 + mt * 16 + mloc;
            int cb = quad ^ ((row >> 1) & 3);
            afr[mt] = *(const short8*)(&As[row * 32 + cb * 8]);
        }
#pragma unroll
        for (int nt = 0; nt < NT; ++nt) {
            int row = wn * NT * 16 + nt * 16 + mloc;
            int cb = quad ^ ((row >> 1) & 3);
            bfr[nt] = *(const short8*)(&Bs[row * 32 + cb * 8]);
        }
#pragma unroll
        for (int mt = 0; mt < MT; ++mt)
#pragma unroll
            for (int nt = 0; nt < NT; ++nt)
                acc[mt][nt] = __builtin_amdgcn_mfma_f32_16x16x32_bf16(
                    afr[mt], bfr[nt], acc[mt][nt], 0, 0, 0);
    }
    // C/D layout: col = lane&15, row = quad*4 + reg  [verified m89/m91]
#pragma unroll
    for (int mt = 0; mt < MT; ++mt) {
        int grow0 = m0 + wm * MT * 16 + mt * 16 + quad * 4;
#pragma unroll
        for (int nt = 0; nt < NT; ++nt) {
            int gcol = n0 + wn * NT * 16 + nt * 16 + mloc;
#pragma unroll
            for (int r = 0; r < 4; ++r) {
                size_t idx = (size_t)(grow0 + r) * N + gcol;
                float v = acc[mt][nt][r];
                if (OUT_BF16) ((u16*)Cv)[idx] = f2bf(v);
                else          ((float*)Cv)[idx] = v;
            }
        }
    }
}

// ---------- split-K MFMA GEMM, f32 atomic-add epilogue ---------------------
// grid (M/BM, N/BN, nslices); kbase = blockIdx.z * KSLICE. A,B row stride = K.
// ADD_X: kz==0 block also adds X (residual) before the atomic.
template<int MT, int NT, int KSLICE, bool ADD_X>
__global__ __launch_bounds__(256) void gemm_splitk(
    const u16* __restrict__ A, const u16* __restrict__ B,
    const float* __restrict__ X, float* __restrict__ Cout, int K, int CS)
{
    constexpr int BM = 32 * MT, BN = 32 * NT;
    __shared__ __align__(16) u16 As[BM * 32];
    __shared__ __align__(16) u16 Bs[BN * 32];
    int tid = threadIdx.x, w = tid >> 6, lane = tid & 63;
    int wm = w & 1, wn = w >> 1;
    int m0 = blockIdx.x * BM, n0 = blockIdx.y * BN;
    int kbase = blockIdx.z * KSLICE;
    int mloc = lane & 15, quad = lane >> 4;
    int lr = lane >> 2, lc = lane & 3;
    f32x4 acc[MT][NT] = {};

    for (int k0 = 0; k0 < KSLICE; k0 += 32) {
        __syncthreads();
#pragma unroll
        for (int j = w; j < 2 * MT; j += 4) {
            int row = j * 16 + lr;
            int cb = lc ^ ((row >> 1) & 3);
            g2lds16(A + (size_t)(m0 + row) * K + kbase + k0 + cb * 8, &As[j * 512]);
        }
#pragma unroll
        for (int j = w; j < 2 * NT; j += 4) {
            int row = j * 16 + lr;
            int cb = lc ^ ((row >> 1) & 3);
            g2lds16(B + (size_t)(n0 + row) * K + kbase + k0 + cb * 8, &Bs[j * 512]);
        }
        __syncthreads();
        short8 afr[MT], bfr[NT];
#pragma unroll
        for (int mt = 0; mt < MT; ++mt) {
            int row = wm * MT * 16 + mt * 16 + mloc;
            int cb = quad ^ ((row >> 1) & 3);
            afr[mt] = *(const short8*)(&As[row * 32 + cb * 8]);
        }
#pragma unroll
        for (int nt = 0; nt < NT; ++nt) {
            int row = wn * NT * 16 + nt * 16 + mloc;
            int cb = quad ^ ((row >> 1) & 3);
            bfr[nt] = *(const short8*)(&Bs[row * 32 + cb * 8]);
        }
#pragma unroll
        for (int mt = 0; mt < MT; ++mt)
#pragma unroll
            for (int nt = 0; nt < NT; ++nt)
                acc[mt][nt] = __builtin_amdgcn_mfma_f32_16x16x32_bf16(
                    afr[mt], bfr[nt], acc[mt][nt], 0, 0, 0);
    }
#pragma unroll
    for (int mt = 0; mt < MT; ++mt) {
        int grow0 = m0 + wm * MT * 16 + mt * 16 + quad * 4;
#pragma unroll
        for (int nt = 0; nt < NT; ++nt) {
            int gcol = n0 + wn * NT * 16 + nt * 16 + mloc;
#pragma unroll
            for (int r = 0; r < 4; ++r) {
                size_t idx = (size_t)(grow0 + r) * CS + gcol;
                float v = acc[mt][nt][r];
                if (ADD_X && blockIdx.z == 0) v += X[idx];
                unsafeAtomicAdd(&Cout[idx], v);
            }
        }
    }
}

// ---------------- dt GEMM: dt = softplus(xdbl[:, :64] @ Wdt_pad^T + b) -----
__global__ __launch_bounds__(256) void dtgemm_k(
    const float* __restrict__ xdbl, const u16* __restrict__ Wdt,
    const float* __restrict__ bias, u16* __restrict__ dtout)
{
    __shared__ __align__(16) u16 Bs[64 * 72];
    int tid = threadIdx.x, wave = tid >> 6, lane = tid & 63;
    int m0 = blockIdx.x * 64, n0 = blockIdx.y * 64;
    int mloc = lane & 15, quad = lane >> 4;
    {
        int r = tid >> 3, ck = (tid & 7) * 8;
#pragma unroll
        for (int rr = 0; rr < 64; rr += 32) {
            int4 bv = *(const int4*)(Wdt + (size_t)(n0 + r + rr) * 64 + ck);
            *(int4*)(&Bs[(r + rr) * 72 + ck]) = bv;
        }
    }
    int arow = m0 + wave * 16 + mloc;
    const float* ar = xdbl + (size_t)arow * XDS + quad * 8;
    short8 af[2];
#pragma unroll
    for (int h = 0; h < 2; ++h) {
        float4 a0 = *(const float4*)(ar + h * 32);
        float4 a1 = *(const float4*)(ar + h * 32 + 4);
        short8 t;
        t[0]=(short)f2bf(a0.x); t[1]=(short)f2bf(a0.y);
        t[2]=(short)f2bf(a0.z); t[3]=(short)f2bf(a0.w);
        t[4]=(short)f2bf(a1.x); t[5]=(short)f2bf(a1.y);
        t[6]=(short)f2bf(a1.z); t[7]=(short)f2bf(a1.w);
        af[h] = t;
    }
    __syncthreads();
    f32x4 acc[4] = {};
#pragma unroll
    for (int h = 0; h < 2; ++h)
#pragma unroll
        for (int nt = 0; nt < 4; ++nt) {
            short8 bf = *(const short8*)(&Bs[(nt * 16 + mloc) * 72 + h * 32 + quad * 8]);
            acc[nt] = __builtin_amdgcn_mfma_f32_16x16x32_bf16(af[h], bf, acc[nt], 0, 0, 0);
        }
#pragma unroll
    for (int nt = 0; nt < 4; ++nt) {
        int gcol = n0 + nt * 16 + mloc;
        int grow = m0 + wave * 16 + quad * 4;
#pragma unroll
        for (int r = 0; r < 4; ++r) {
            float t = acc[nt][r] + bias[gcol];
            float sp = (t > 15.f) ? t : __logf(1.f + __expf(t));
            dtout[(size_t)(grow + r) * D_INNER + gcol] = f2bf(sp);
        }
    }
}

// ---------------- depthwise causal conv4 + SiLU (4-wide in c) --------------
__global__ __launch_bounds__(256) void conv_silu_k(
    const u16* __restrict__ xz, const float* __restrict__ cw,
    const float* __restrict__ cb, u16* __restrict__ xc)
{
    int gid = blockIdx.x * 256 + threadIdx.x;     // NROW * D_INNER/4
    int r = gid / (D_INNER / 4);
    int c4 = (gid - r * (D_INNER / 4)) * 4;
    int t = r & (SEQ - 1);
    float4 cbv = *(const float4*)(cb + c4);
    float acc[4] = {cbv.x, cbv.y, cbv.z, cbv.w};
    float4 wv[4];
#pragma unroll
    for (int j = 0; j < 4; ++j) wv[j] = *(const float4*)(cw + (c4 + j) * 4);
#pragma unroll
    for (int k = 0; k < 4; ++k) {
        int tt = t - 3 + k;
        if (tt >= 0) {
            ushort4 xv = *(const ushort4*)(xz + (size_t)(r - 3 + k) * D_XZ + c4);
            acc[0] += bf2f(xv.x) * ((const float*)&wv[0])[k];
            acc[1] += bf2f(xv.y) * ((const float*)&wv[1])[k];
            acc[2] += bf2f(xv.z) * ((const float*)&wv[2])[k];
            acc[3] += bf2f(xv.w) * ((const float*)&wv[3])[k];
        }
    }
    ushort4 o;
    o.x = f2bf(acc[0] / (1.f + __expf(-acc[0])));
    o.y = f2bf(acc[1] / (1.f + __expf(-acc[1])));
    o.z = f2bf(acc[2] / (1.f + __expf(-acc[2])));
    o.w = f2bf(acc[3] / (1.f + __expf(-acc[3])));
    *(ushort4*)(xc + (size_t)r * D_INNER + c4) = o;
}

// ================= chunked parallel scan (CLEN=8, LDS-staged B/C) ==========
__global__ __launch_bounds__(256) void scan_p1(
    const u16* __restrict__ dt, const u16* __restrict__ xc,
    const float* __restrict__ xdbl, const float* __restrict__ negA,
    float* __restrict__ Sbuf, float* __restrict__ dtsumbuf)
{
    __shared__ float Bsh[CLEN][D_STATE];
    int tid = threadIdx.x;
    int gid = blockIdx.x * 256 + tid;
    int d = gid % D_INNER;
    int bcN = gid / D_INNER;
    int c = bcN % NCHUNK, b = bcN / NCHUNK;
    size_t r0 = (size_t)b * SEQ + c * CLEN;
    if (tid < CLEN * D_STATE) {
        int tt = tid >> 4, n = tid & 15;
        Bsh[tt][n] = xdbl[(r0 + tt) * XDS + DT_RANK + n];
    }
    float a[D_STATE], s[D_STATE] = {};
    {
        const float4* Ar = (const float4*)(negA + d * D_STATE);
        float4 a0 = Ar[0], a1 = Ar[1], a2 = Ar[2], a3 = Ar[3];
        a[0]=a0.x; a[1]=a0.y; a[2]=a0.z; a[3]=a0.w;
        a[4]=a1.x; a[5]=a1.y; a[6]=a1.z; a[7]=a1.w;
        a[8]=a2.x; a[9]=a2.y; a[10]=a2.z; a[11]=a2.w;
        a[12]=a3.x; a[13]=a3.y; a[14]=a3.z; a[15]=a3.w;
    }
    float dtv[CLEN], du[CLEN];
    const u16* dp = dt + r0 * D_INNER + d;
    const u16* xp = xc + r0 * D_INNER + d;
#pragma unroll
    for (int t = 0; t < CLEN; ++t) {
        dtv[t] = bf2f(dp[t * D_INNER]);
        du[t] = dtv[t] * bf2f(xp[t * D_INNER]);
    }
    __syncthreads();
    float dtsum = 0.f;
#pragma unroll
    for (int t = 0; t < CLEN; ++t) {
        dtsum += dtv[t];
#pragma unroll
        for (int n = 0; n < D_STATE; ++n)
            s[n] = __expf(dtv[t] * a[n]) * s[n] + du[t] * Bsh[t][n];
    }
    float4* So = (float4*)(Sbuf + (size_t)gid * D_STATE);
#pragma unroll
    for (int j = 0; j < 4; ++j)
        So[j] = make_float4(s[j*4], s[j*4+1], s[j*4+2], s[j*4+3]);
    dtsumbuf[gid] = dtsum;
}

__global__ __launch_bounds__(256) void scan_p2(
    const float* __restrict__ Sbuf, const float* __restrict__ dtsumbuf,
    const float* __restrict__ negA, float* __restrict__ carry)
{
    int gid = blockIdx.x * 256 + threadIdx.x;   // B*D_INNER*16
    int n = gid % D_STATE;
    int d = (gid / D_STATE) % D_INNER;
    int b = gid / (D_STATE * D_INNER);
    float a = negA[d * D_STATE + n];
    float s = 0.f;
#pragma unroll 8
    for (int c = 0; c < NCHUNK; ++c) {
        size_t idx = ((size_t)(b * NCHUNK + c) * D_INNER + d);
        carry[idx * D_STATE + n] = s;
        s = Sbuf[idx * D_STATE + n] + __expf(a * dtsumbuf[idx]) * s;
    }
}

__global__ __launch_bounds__(256) void scan_p3(
    const u16* __restrict__ dt, const u16* __restrict__ xc,
    const u16* __restrict__ xz, const float* __restrict__ xdbl,
    const float* __restrict__ negA, const float* __restrict__ Dp,
    const float* __restrict__ carry, u16* __restrict__ yy)
{
    __shared__ float BCsh[CLEN][2 * D_STATE];
    int tid = threadIdx.x;
    int gid = blockIdx.x * 256 + tid;
    int d = gid % D_INNER;
    int bcN = gid / D_INNER;
    int c = bcN % NCHUNK, b = bcN / NCHUNK;
    size_t r0 = (size_t)b * SEQ + c * CLEN;
    {
        int tt = tid >> 5, j = tid & 31;   // 256 = 8 rows x 32 vals
        BCsh[tt][j] = xdbl[(r0 + tt) * XDS + DT_RANK + j];
    }
    float a[D_STATE], s[D_STATE];
    {
        const float4* Ci = (const float4*)(carry + (size_t)gid * D_STATE);
        float4 c0 = Ci[0], c1 = Ci[1], c2 = Ci[2], c3 = Ci[3];
        s[0]=c0.x; s[1]=c0.y; s[2]=c0.z; s[3]=c0.w;
        s[4]=c1.x; s[5]=c1.y; s[6]=c1.z; s[7]=c1.w;
        s[8]=c2.x; s[9]=c2.y; s[10]=c2.z; s[11]=c2.w;
        s[12]=c3.x; s[13]=c3.y; s[14]=c3.z; s[15]=c3.w;
        const float4* Ar = (const float4*)(negA + d * D_STATE);
        float4 a0 = Ar[0], a1 = Ar[1], a2 = Ar[2], a3 = Ar[3];
        a[0]=a0.x; a[1]=a0.y; a[2]=a0.z; a[3]=a0.w;
        a[4]=a1.x; a[5]=a1.y; a[6]=a1.z; a[7]=a1.w;
        a[8]=a2.x; a[9]=a2.y; a[10]=a2.z; a[11]=a2.w;
        a[12]=a3.x; a[13]=a3.y; a[14]=a3.z; a[15]=a3.w;
    }
    float dtv[CLEN], xcv[CLEN], zv[CLEN];
    const u16* dp = dt + r0 * D_INNER + d;
    const u16* xp = xc + r0 * D_INNER + d;
    const u16* zp = xz + r0 * D_XZ + D_INNER + d;
#pragma unroll
    for (int t = 0; t < CLEN; ++t) {
        dtv[t] = bf2f(dp[t * D_INNER]);
        xcv[t] = bf2f(xp[t * D_INNER]);
        zv[t]  = bf2f(zp[t * D_XZ]);
    }
    float dpv = Dp[d];
    __syncthreads();
    u16* yp = yy + r0 * D_INNER + d;
#pragma unroll
    for (int t = 0; t < CLEN; ++t) {
        float du = dtv[t] * xcv[t];
        float y = 0.f;
#pragma unroll
        for (int n = 0; n < D_STATE; ++n) {
            s[n] = __expf(dtv[t] * a[n]) * s[n] + du * BCsh[t][n];
            y += s[n] * BCsh[t][D_STATE + n];
        }
        float yv = y + dpv * xcv[t];
        float sig = 1.f / (1.f + __expf(-zv[t]));
        yp[t * D_INNER] = f2bf(yv * (zv[t] * sig));
    }
}

extern "C" void kernel_launch(void* const* d_in, const int* in_sizes, int n_in,
                              void* d_out, int out_size, void* d_ws, size_t ws_size,
                              hipStream_t stream) {
    const float* x      = (const float*)d_in[0];
    const float* ln_g   = (const float*)d_in[1];
    const float* ln_b   = (const float*)d_in[2];
    const float* W_in   = (const float*)d_in[3];
    const float* conv_w = (const float*)d_in[4];
    const float* conv_b = (const float*)d_in[5];
    const float* W_xp   = (const float*)d_in[6];
    const float* W_dt   = (const float*)d_in[7];
    const float* b_dt   = (const float*)d_in[8];
    const float* A_log  = (const float*)d_in[9];
    const float* Dp     = (const float*)d_in[10];
    const float* W_out  = (const float*)d_in[11];
    float* out = (float*)d_out;

    char* ws = (char*)d_ws;
    u16*   h_bf    = (u16*)ws;   ws += (size_t)NROW * D_MODEL * 2;
    u16*   xz_bf   = (u16*)ws;   ws += (size_t)NROW * D_XZ * 2;
    u16*   xc_bf   = (u16*)ws;   ws += (size_t)NROW * D_INNER * 2;
    float* xdbl    = (float*)ws; ws += (size_t)NROW * XDS * 4;
    u16*   dtbuf   = (u16*)ws;   ws += (size_t)NROW * D_INNER * 2;
    u16*   yybuf   = (u16*)ws;   ws += (size_t)NROW * D_INNER * 2;
    u16*   Win_bf  = (u16*)ws;   ws += (size_t)D_XZ * D_MODEL * 2;
    u16*   Wout_bf = (u16*)ws;   ws += (size_t)D_MODEL * D_INNER * 2;
    u16*   Wxp_bf  = (u16*)ws;   ws += (size_t)XDS * D_INNER * 2;
    u16*   Wdt_bf  = (u16*)ws;   ws += (size_t)D_INNER * 64 * 2;
    float* negA    = (float*)ws; ws += (size_t)D_INNER * D_STATE * 4;
    float* Sbuf    = (float*)ws; ws += (size_t)2 * NCHUNK * D_INNER * 16 * 4;
    float* dtsumb  = (float*)ws; ws += (size_t)2 * NCHUNK * D_INNER * 4;
    float* carryb  = (float*)ws;

    // prep: LN rows (2048 blocks) + weight-convert/zeroing (5560 blocks)
    prep_ln_k<<<NROW + PREP_BLOCKS, 256, 0, stream>>>(
        x, ln_g, ln_b, h_bf, W_in, W_out, W_xp, W_dt, A_log,
        Win_bf, Wout_bf, Wxp_bf, Wdt_bf, negA, xdbl, out);

    // GEMM1: 2048x3072x768, 128x64 tiles -> 768 blocks (3/CU)
    gemm128<4, 2, true><<<dim3(NROW / 128, D_XZ / 64), 256, 0, stream>>>(
        h_bf, Win_bf, xz_bf, NROW, D_XZ, D_MODEL);
    conv_silu_k<<<NROW * (D_INNER / 4) / 256, 256, 0, stream>>>(
        xz_bf, conv_w, conv_b, xc_bf);
    // xproj: 64x128 tile, split-K x8 (slice 192) -> 256 blocks
    gemm_splitk<2, 4, 192, false><<<dim3(NROW / 64, 1, 8), 256, 0, stream>>>(
        xc_bf, Wxp_bf, nullptr, xdbl, D_INNER, XDS);
    // dt: 2048x1536x64, bf16 out; 768 blocks
    dtgemm_k<<<dim3(NROW / 64, D_INNER / 64), 256, 0, stream>>>(
        xdbl, Wdt_bf, b_dt, dtbuf);

    scan_p1<<<2 * NCHUNK * D_INNER / 256, 256, 0, stream>>>(
        dtbuf, xc_bf, xdbl, negA, Sbuf, dtsumb);
    scan_p2<<<2 * D_INNER * D_STATE / 256, 256, 0, stream>>>(
        Sbuf, dtsumb, negA, carryb);
    scan_p3<<<2 * NCHUNK * D_INNER / 256, 256, 0, stream>>>(
        dtbuf, xc_bf, xz_bf, xdbl, negA, Dp, carryb, yybuf);

    // GEMM-out: 2048x768x1536, 64x64 tiles, split-K x2 -> 768 blocks; +x via kz==0
    gemm_splitk<2, 2, 768, true><<<dim3(NROW / 64, D_MODEL / 64, 2), 256, 0, stream>>>(
        yybuf, Wout_bf, x, out, D_INNER, D_MODEL);
}